// Round 23
// baseline (474.289 us; speedup 1.0000x reference)
//
#include <hip/hip_runtime.h>
#include <stdint.h>

#define DEV __device__ __forceinline__

typedef unsigned short u16;
typedef unsigned int u32;
using f32x4 = __attribute__((ext_vector_type(4))) float;
using u32x4 = __attribute__((ext_vector_type(4))) u32;
using bf16x8 = __attribute__((ext_vector_type(8))) __bf16;

DEV float b2f(u16 u) { u32 x = ((u32)u) << 16; return __builtin_bit_cast(float, x); }
DEV u16 f2b(float f) {
  u32 x = __builtin_bit_cast(u32, f);
  return (u16)((x + 0x7FFFu + ((x >> 16) & 1u)) >> 16);
}
DEV u32 pk2(float a, float b) { return (u32)f2b(a) | ((u32)f2b(b) << 16); }
DEV bf16x8 lds_frag(const u16* p) { return __builtin_bit_cast(bf16x8, *(const u32x4*)p); }
DEV bf16x8 g_frag(const u16* p) { return __builtin_bit_cast(bf16x8, *(const u32x4*)p); }
DEV f32x4 mfma16(bf16x8 a, bf16x8 b, f32x4 c) {
  return __builtin_amdgcn_mfma_f32_16x16x32_bf16(a, b, c, 0, 0, 0);
}
DEV float wredmax(float v) {
#pragma unroll
  for (int m = 32; m > 0; m >>= 1) v = fmaxf(v, __shfl_xor(v, m));
  return v;
}
DEV float wredsum(float v) {
#pragma unroll
  for (int m = 32; m > 0; m >>= 1) v += __shfl_xor(v, m);
  return v;
}

// ---------------- LayerNorm: x[16384][512] f32 -> xn bf16 ----------------
__global__ __launch_bounds__(256) void ln_k(const float* __restrict__ x,
                                            const float* __restrict__ gamma,
                                            const float* __restrict__ beta,
                                            u16* __restrict__ xn) {
  int row = blockIdx.x, tid = threadIdx.x;
  int lane = tid & 63, wave = tid >> 6;
  const float* xr = x + (size_t)row * 512;
  float a = xr[2 * tid], b = xr[2 * tid + 1];
  __shared__ float red[8];
  float s = wredsum(a + b);
  if (lane == 0) red[wave] = s;
  __syncthreads();
  float mean = (red[0] + red[1] + red[2] + red[3]) * (1.0f / 512.0f);
  float da = a - mean, db = b - mean;
  float vs = wredsum(da * da + db * db);
  if (lane == 0) red[4 + wave] = vs;
  __syncthreads();
  float var = (red[4] + red[5] + red[6] + red[7]) * (1.0f / 512.0f);
  float rstd = rsqrtf(var + 1e-5f);
  int c = 2 * tid;
  u16 o0 = f2b(da * rstd * gamma[c] + beta[c]);
  u16 o1 = f2b(db * rstd * gamma[c + 1] + beta[c + 1]);
  *(u32*)&xn[(size_t)row * 512 + c] = (u32)o0 | ((u32)o1 << 16);
}

// ------------- transpose f32 [R][C] -> bf16 [C][R] (weights) -------------
__global__ __launch_bounds__(256) void transpose_w(const float* __restrict__ in,
                                                   u16* __restrict__ out, int R, int C) {
  __shared__ float t[64][65];
  int c0 = blockIdx.x * 64, r0 = blockIdx.y * 64;
  int tid = threadIdx.x;
  int r = tid >> 2, cs = (tid & 3) * 16;
  const float* src = in + (size_t)(r0 + r) * C + c0 + cs;
#pragma unroll
  for (int e = 0; e < 16; e++) t[r][cs + e] = src[e];
  __syncthreads();
  int c = tid >> 2, rs = (tid & 3) * 16;
  u16* dst = out + (size_t)(c0 + c) * R + r0 + rs;
#pragma unroll
  for (int e = 0; e < 16; e++) dst[e] = f2b(t[rs + e][c]);
}

// ------------- transpose bf16 src[bh][4096][64] -> dst[bh][64][4096] -------------
__global__ __launch_bounds__(256) void transpose_k(const u16* __restrict__ k,
                                                   u16* __restrict__ kT) {
  __shared__ u16 t[64][72];
  int bh = blockIdx.y, i0 = blockIdx.x * 64;
  int tid = threadIdx.x;
  int r = tid >> 2, ds = (tid & 3) * 16;
  const u16* src = k + (((size_t)bh * 4096) + i0 + r) * 64 + ds;
#pragma unroll
  for (int e = 0; e < 16; e++) t[r][ds + e] = src[e];
  __syncthreads();
  int d = tid >> 2, is = (tid & 3) * 16;
  u16* dst = kT + ((size_t)bh * 64 + d) * 4096 + i0 + is;
#pragma unroll
  for (int e = 0; e < 16; e++) dst[e] = t[is + e][d];
}

// ------------- landmark means -> hi/lo planes + optional frag-ordered hi copy -------------
__global__ __launch_bounds__(256) void landmark_mean(const u16* __restrict__ src,
                                                     u16* __restrict__ dh,
                                                     u16* __restrict__ dl,
                                                     u16* __restrict__ dF) {
  int gid = blockIdx.x * 4 + (threadIdx.x >> 6);
  int lane = threadIdx.x & 63;
  int bh = gid >> 8, lm = gid & 255;
  const u16* p = src + (((size_t)bh * 4096) + lm * 16) * 64 + lane;
  float s = 0.f;
#pragma unroll
  for (int t = 0; t < 16; t++) s += b2f(p[t * 64]);
  float m = s * (1.0f / 16.0f);
  u16 hi = f2b(m);
  size_t idx = ((size_t)bh * 256 + lm) * 64 + lane;
  dh[idx] = hi;
  dl[idx] = f2b(m - b2f(hi));
  if (dF) {
    size_t a = ((((size_t)bh * 16 + (lm >> 4)) * 2 + (lane >> 5)) * 512) +
               (((lane >> 3) & 3) * 128) + ((lm & 15) * 8) + (lane & 7);
    dF[a] = hi;
  }
}

// ---------------- big bf16 NT GEMM: C = A[M][K] * Bt[N][K]^T ----------------
// Direct-store epilogue + register prefetch; BK=64 (8 K-steps for K=512).
template <int MODE>
__global__ __launch_bounds__(256) void gemm_bf16_nt(
    const u16* __restrict__ A, const u16* __restrict__ Bt, int K,
    u16* __restrict__ oq, u16* __restrict__ ok, u16* __restrict__ ov,
    const float* __restrict__ xres, const float* __restrict__ bias,
    float* __restrict__ oc) {
  constexpr int BM = 128, BN = 128, BK = 64, LDT = BK + 8;
  __shared__ __align__(16) u16 Al[BM][LDT];
  __shared__ __align__(16) u16 Bl[BN][LDT];
  int tid = threadIdx.x;
  int lane = tid & 63, wave = tid >> 6;
  int bm = blockIdx.x * BM, bn = blockIdx.y * BN;
  int wm = (wave >> 1) * 64, wn = (wave & 1) * 64;
  int l15 = lane & 15, g = lane >> 4;
  // staging: thread covers rows r and r+64, col chunk c16 (16 u16 = 2 x u32x4)
  int r = tid >> 2, c16 = (tid & 3) * 16;
  auto srcA = [&](int rr, int kc, int kt) -> const u16* {
    if (MODE == 0) return A + (size_t)(bm + rr) * K + kt + kc;
    int m = bm + rr, kk = kt + kc;
    return A + ((((size_t)(m >> 12)) * 8 + (kk >> 6)) * 4096 + (m & 4095)) * 64 + (kk & 63);
  };
  u32x4 a00 = *(const u32x4*)srcA(r, c16, 0);
  u32x4 a01 = *(const u32x4*)(srcA(r, c16, 0) + 8);
  u32x4 a10 = *(const u32x4*)srcA(r + 64, c16, 0);
  u32x4 a11 = *(const u32x4*)(srcA(r + 64, c16, 0) + 8);
  const u16* pb0 = Bt + (size_t)(bn + r) * K + c16;
  const u16* pb1 = Bt + (size_t)(bn + r + 64) * K + c16;
  u32x4 b00 = *(const u32x4*)pb0;
  u32x4 b01 = *(const u32x4*)(pb0 + 8);
  u32x4 b10 = *(const u32x4*)pb1;
  u32x4 b11 = *(const u32x4*)(pb1 + 8);
  f32x4 acc[4][4] = {};
  for (int kt = 0; kt < K; kt += BK) {
    __syncthreads();
    *(u32x4*)&Al[r][c16] = a00;
    *(u32x4*)&Al[r][c16 + 8] = a01;
    *(u32x4*)&Al[r + 64][c16] = a10;
    *(u32x4*)&Al[r + 64][c16 + 8] = a11;
    *(u32x4*)&Bl[r][c16] = b00;
    *(u32x4*)&Bl[r][c16 + 8] = b01;
    *(u32x4*)&Bl[r + 64][c16] = b10;
    *(u32x4*)&Bl[r + 64][c16 + 8] = b11;
    __syncthreads();
    if (kt + BK < K) {
      int kn = kt + BK;
      a00 = *(const u32x4*)srcA(r, c16, kn);
      a01 = *(const u32x4*)(srcA(r, c16, kn) + 8);
      a10 = *(const u32x4*)srcA(r + 64, c16, kn);
      a11 = *(const u32x4*)(srcA(r + 64, c16, kn) + 8);
      b00 = *(const u32x4*)(pb0 + kn);
      b01 = *(const u32x4*)(pb0 + kn + 8);
      b10 = *(const u32x4*)(pb1 + kn);
      b11 = *(const u32x4*)(pb1 + kn + 8);
    }
#pragma unroll
    for (int ks = 0; ks < 2; ks++) {
      int ko = ks * 32 + 8 * g;
      bf16x8 af[4], bf_[4];
#pragma unroll
      for (int i = 0; i < 4; i++) af[i] = lds_frag(&Al[wm + i * 16 + l15][ko]);
#pragma unroll
      for (int i = 0; i < 4; i++) bf_[i] = lds_frag(&Bl[wn + i * 16 + l15][ko]);
#pragma unroll
      for (int mi = 0; mi < 4; mi++)
#pragma unroll
        for (int ni = 0; ni < 4; ni++) acc[mi][ni] = mfma16(af[mi], bf_[ni], acc[mi][ni]);
    }
  }
  if (MODE == 0) {
    int tensor = bn / 512;
    float scale = (tensor == 0) ? 0.125f : 1.0f;
    u16* base = (tensor == 0) ? oq : (tensor == 1 ? ok : ov);
#pragma unroll
    for (int mi = 0; mi < 4; mi++)
#pragma unroll
      for (int ni = 0; ni < 4; ni++) {
        int cw = (bn % 512) + wn + ni * 16 + l15;
        int h = cw >> 6, d = cw & 63;
#pragma unroll
        for (int rr = 0; rr < 4; rr++) {
          int m = bm + wm + mi * 16 + 4 * g + rr;
          int b = m >> 12, i = m & 4095;
          base[(((size_t)(b * 8 + h)) * 4096 + i) * 64 + d] = f2b(acc[mi][ni][rr] * scale);
        }
      }
  } else {
#pragma unroll
    for (int mi = 0; mi < 4; mi++)
#pragma unroll
      for (int ni = 0; ni < 4; ni++) {
        int col = bn + wn + ni * 16 + l15;
#pragma unroll
        for (int rr = 0; rr < 4; rr++) {
          int m = bm + wm + mi * 16 + 4 * g + rr;
          oc[(size_t)m * 512 + col] =
              acc[mi][ni][rr] + xres[(size_t)m * 512 + col] + bias[col];
        }
      }
  }
}

// ---------------- NS-chain GEMM, 64x64 tile, templated BK ----------------
// BK=128 for K=256 dispatches (2 K-tiles, 4 barriers); BK=64 for K=64.
// PREC=1: hi/lo inputs (3 MFMA/product). PREC=0: hi-only (1 MFMA/product).
template <int OMODE, int PREC, int BK>
__global__ __launch_bounds__(256) void ns_gemm(
    const u16* __restrict__ Ahg, const u16* __restrict__ Alg,
    const u16* __restrict__ Bhg, const u16* __restrict__ Blg, int K, int sA, int sB,
    u16* __restrict__ Ch, u16* __restrict__ Cl2, u16* __restrict__ Th, u16* __restrict__ Tl,
    float* __restrict__ Cf, u16* __restrict__ Tu,
    float cC, float aC, float cT, float aT, int wrC, int wrT) {
  constexpr int LDT = BK + 8;
  constexpr int NC = BK / 32;  // u32x4 chunks per thread per matrix
  __shared__ __align__(16) u16 Ahs[64][LDT], Bhs[64][LDT];
  __shared__ __align__(16) u16 Als[PREC ? 64 : 2][LDT], Bls[PREC ? 64 : 2][LDT];
  int bz = blockIdx.z;
  int tid = threadIdx.x, lane = tid & 63, wave = tid >> 6;
  int l15 = lane & 15, g = lane >> 4;
  int bm = blockIdx.x * 64, bn = blockIdx.y * 64;
  int wm = (wave >> 1) * 32, wn = (wave & 1) * 32;
  const u16* Ah0 = Ahg + (size_t)bz * sA;
  const u16* Al0 = Alg + (size_t)bz * sA;
  const u16* Bh0 = Bhg + (size_t)bz * sB;
  const u16* Bl0 = Blg + (size_t)bz * sB;
  int r = tid >> 2, cb = (tid & 3) * (BK / 4);
  const u16* pa = Ah0 + (size_t)(bm + r) * K + cb;
  const u16* pal = Al0 + (size_t)(bm + r) * K + cb;
  const u16* pb = Bh0 + (size_t)(bn + r) * K + cb;
  const u16* pbl = Bl0 + (size_t)(bn + r) * K + cb;
  u32x4 ra[NC], rc[NC], rb[NC], rd[NC];
#pragma unroll
  for (int c = 0; c < NC; c++) {
    ra[c] = *(const u32x4*)(pa + c * 8);
    rc[c] = *(const u32x4*)(pb + c * 8);
    if (PREC) {
      rb[c] = *(const u32x4*)(pal + c * 8);
      rd[c] = *(const u32x4*)(pbl + c * 8);
    }
  }
  f32x4 acc[2][2] = {};
  int nt = K / BK;
  for (int t = 0; t < nt; t++) {
    __syncthreads();
#pragma unroll
    for (int c = 0; c < NC; c++) {
      *(u32x4*)&Ahs[r][cb + c * 8] = ra[c];
      *(u32x4*)&Bhs[r][cb + c * 8] = rc[c];
      if (PREC) {
        *(u32x4*)&Als[r][cb + c * 8] = rb[c];
        *(u32x4*)&Bls[r][cb + c * 8] = rd[c];
      }
    }
    __syncthreads();
    if (t + 1 < nt) {
      int kt = (t + 1) * BK;
#pragma unroll
      for (int c = 0; c < NC; c++) {
        ra[c] = *(const u32x4*)(pa + kt + c * 8);
        rc[c] = *(const u32x4*)(pb + kt + c * 8);
        if (PREC) {
          rb[c] = *(const u32x4*)(pal + kt + c * 8);
          rd[c] = *(const u32x4*)(pbl + kt + c * 8);
        }
      }
    }
#pragma unroll
    for (int ks = 0; ks < BK / 32; ks++) {
      int ko = ks * 32 + 8 * g;
      bf16x8 ah[2], al[2], bh_[2], bl_[2];
#pragma unroll
      for (int i = 0; i < 2; i++) {
        int ro = wm + i * 16 + l15;
        int rn = wn + i * 16 + l15;
        ah[i] = lds_frag(&Ahs[ro][ko]);
        bh_[i] = lds_frag(&Bhs[rn][ko]);
        if (PREC) {
          al[i] = lds_frag(&Als[ro][ko]);
          bl_[i] = lds_frag(&Bls[rn][ko]);
        }
      }
#pragma unroll
      for (int mi = 0; mi < 2; mi++)
#pragma unroll
        for (int ni = 0; ni < 2; ni++) {
          acc[mi][ni] = mfma16(ah[mi], bh_[ni], acc[mi][ni]);
          if (PREC) {
            acc[mi][ni] = mfma16(ah[mi], bl_[ni], acc[mi][ni]);
            acc[mi][ni] = mfma16(al[mi], bh_[ni], acc[mi][ni]);
          }
        }
    }
  }
#pragma unroll
  for (int mi = 0; mi < 2; mi++)
#pragma unroll
    for (int ni = 0; ni < 2; ni++) {
      int r0 = bm + wm + mi * 16 + 4 * g;
      int cg = bn + wn + ni * 16 + l15;
      f32x4 a = acc[mi][ni];
      if (OMODE == 1) {
        float* c = Cf + (size_t)bz * 65536;
#pragma unroll
        for (int rr = 0; rr < 4; rr++)
          c[(size_t)(r0 + rr) * 256 + cg] = aC * a[rr] + ((r0 + rr) == cg ? cC : 0.f);
      } else if (OMODE == 2) {
        u16 pp[4];
#pragma unroll
        for (int rr = 0; rr < 4; rr++) pp[rr] = f2b(aT * a[rr]);
        u16* tp = Tu + ((((size_t)bz * 4 + (cg >> 4)) * 8 + (r0 >> 5)) * 512) +
                  (((r0 >> 3) & 3) * 128) + ((cg & 15) * 8) + (r0 & 7);
        *(u32*)tp = (u32)pp[0] | ((u32)pp[1] << 16);
        *(u32*)(tp + 2) = (u32)pp[2] | ((u32)pp[3] << 16);
      } else {
        if (wrC) {
#pragma unroll
          for (int rr = 0; rr < 4; rr++) {
            float v = aC * a[rr] + ((r0 + rr) == cg ? cC : 0.f);
            u16 hi = f2b(v);
            size_t idx = (size_t)bz * 65536 + (size_t)(r0 + rr) * 256 + cg;
            Ch[idx] = hi;
            Cl2[idx] = f2b(v - b2f(hi));
          }
        }
        if (wrT) {
          u16 ph[4], pl[4];
#pragma unroll
          for (int rr = 0; rr < 4; rr++) {
            float v = aT * a[rr] + ((r0 + rr) == cg ? cT : 0.f);
            ph[rr] = f2b(v);
            pl[rr] = f2b(v - b2f(ph[rr]));
          }
          size_t idx = (size_t)bz * 65536 + (size_t)cg * 256 + r0;
          *(u32*)&Th[idx] = (u32)ph[0] | ((u32)ph[1] << 16);
          *(u32*)&Th[idx + 2] = (u32)ph[2] | ((u32)ph[3] << 16);
          *(u32*)&Tl[idx] = (u32)pl[0] | ((u32)pl[1] << 16);
          *(u32*)&Tl[idx + 2] = (u32)pl[2] | ((u32)pl[3] << 16);
        }
      }
    }
}

// ---------------- row softmax over 256 (in place) + hi/lo plane output ----------------
__global__ __launch_bounds__(256) void softmax256(float* __restrict__ S,
                                                  u16* __restrict__ Sh,
                                                  u16* __restrict__ Sl) {
  int row = blockIdx.x * 4 + (threadIdx.x >> 6);
  int lane = threadIdx.x & 63;
  float* r = S + (size_t)row * 256;
  f32x4 vv = *(f32x4*)&r[lane * 4];
  float mx = wredmax(fmaxf(fmaxf(vv[0], vv[1]), fmaxf(vv[2], vv[3])));
  vv[0] = __expf(vv[0] - mx);
  vv[1] = __expf(vv[1] - mx);
  vv[2] = __expf(vv[2] - mx);
  vv[3] = __expf(vv[3] - mx);
  float sm = wredsum(vv[0] + vv[1] + vv[2] + vv[3]);
  vv *= (1.0f / sm);
  *(f32x4*)&r[lane * 4] = vv;
  u16 h[4], l[4];
#pragma unroll
  for (int e = 0; e < 4; e++) {
    h[e] = f2b(vv[e]);
    l[e] = f2b(vv[e] - b2f(h[e]));
  }
  size_t p = (size_t)row * 256 + lane * 4;
  *(u32*)&Sh[p] = (u32)h[0] | ((u32)h[1] << 16);
  *(u32*)&Sh[p + 2] = (u32)h[2] | ((u32)h[3] << 16);
  *(u32*)&Sl[p] = (u32)l[0] | ((u32)l[1] << 16);
  *(u32*)&Sl[p + 2] = (u32)l[2] | ((u32)l[3] << 16);
}

// ---------------- pinv scale, stage 1 ----------------
__global__ __launch_bounds__(256) void pinv_part(const float* __restrict__ mat,
                                                 float* __restrict__ colpart,
                                                 float* __restrict__ scal) {
  int blk = blockIdx.x;
  int bh = blk >> 3, ch = blk & 7;
  const float* m = mat + (size_t)bh * 65536 + (size_t)ch * 32 * 256;
  int tid = threadIdx.x, lane = tid & 63, wv = tid >> 6;
  float cp = 0.f;
#pragma unroll 4
  for (int r2 = 0; r2 < 32; r2++) cp += m[r2 * 256 + tid];
  colpart[(size_t)blk * 256 + tid] = cp;
  float rmax = 0.f;
#pragma unroll
  for (int rr = 0; rr < 8; rr++) {
    f32x4 v = *(const f32x4*)&m[(wv * 8 + rr) * 256 + lane * 4];
    float s = wredsum(v[0] + v[1] + v[2] + v[3]);
    rmax = fmaxf(rmax, s);
  }
  if (lane == 0) atomicMax((int*)&scal[1], __float_as_int(rmax));
}

// ---------------- pinv scale, stage 2 ----------------
__global__ __launch_bounds__(256) void pinv_fin(const float* __restrict__ colpart,
                                                float* __restrict__ scal) {
  int tid = threadIdx.x;
  float mx = 0.f;
  for (int bh = 0; bh < 32; bh++) {
    float s = 0.f;
#pragma unroll
    for (int ch = 0; ch < 8; ch++) s += colpart[((size_t)bh * 8 + ch) * 256 + tid];
    mx = fmaxf(mx, s);
  }
  mx = wredmax(mx);
  __shared__ float red[4];
  if ((tid & 63) == 0) red[tid >> 6] = mx;
  __syncthreads();
  if (tid == 0) {
    float a = fmaxf(fmaxf(red[0], red[1]), fmaxf(red[2], red[3]));
    atomicMax((int*)&scal[0], __float_as_int(a));
  }
}

// ---------------- pinv init: z = matT*s, zT = mat*s  (hi/lo planes) ----------------
__global__ __launch_bounds__(256) void pinv_init(const float* __restrict__ mat,
                                                 const float* __restrict__ scal,
                                                 u16* __restrict__ zh, u16* __restrict__ zl,
                                                 u16* __restrict__ zth, u16* __restrict__ ztl) {
  size_t idx = (size_t)blockIdx.x * 256 + threadIdx.x;
  int bh = (int)(idx >> 16);
  int i = (int)((idx >> 8) & 255), j = (int)(idx & 255);
  float s = 1.0f / (scal[0] * scal[1]);
  float val = mat[idx] * s;
  u16 hi = f2b(val);
  u16 lo = f2b(val - b2f(hi));
  zth[idx] = hi;
  ztl[idx] = lo;
  size_t tixd = ((size_t)bh << 16) + ((size_t)j << 8) + i;
  zh[tixd] = hi;
  zl[tixd] = lo;
}

// ------- attn3 split-KV flash v3: merged ss chains (2x ILP, one LDS round-trip/tile) -------
__global__ __launch_bounds__(512) void attn3_split(const u16* __restrict__ qlh,
                                                   const u16* __restrict__ k,
                                                   const u16* __restrict__ vT,
                                                   float* __restrict__ pacc,
                                                   float* __restrict__ ml) {
  __shared__ __align__(16) u16 kb[64][72];
  __shared__ __align__(16) u16 vtb[64][72];
  __shared__ __align__(16) u16 Pb[8][32][72];
  int tid = threadIdx.x, lane = tid & 63, wv = tid >> 6;
  int l15 = lane & 15, g = lane >> 4;
  int bh = blockIdx.y, kvc = blockIdx.x;
  const u16* kb_g = k + ((size_t)bh * 4096 + (size_t)kvc * 512) * 64;
  const u16* vb_g = vT + (size_t)bh * 64 * 4096 + (size_t)kvc * 512;
  bf16x8 aq[2][2];
#pragma unroll
  for (int ss = 0; ss < 2; ss++) {
    const u16* qlp = qlh + ((size_t)bh * 256 + wv * 32 + ss * 16 + l15) * 64 + 8 * g;
    aq[ss][0] = g_frag(qlp);
    aq[ss][1] = g_frag(qlp + 32);
  }
  int sr = tid >> 3, sc = (tid & 7) * 8;
  u32x4 rk = *(const u32x4*)(kb_g + (size_t)sr * 64 + sc);
  u32x4 rv = *(const u32x4*)(vb_g + (size_t)sr * 4096 + sc);
  f32x4 minit = {-1e30f, -1e30f, -1e30f, -1e30f};
  f32x4 mreg[2] = {minit, minit};
  f32x4 lreg[2] = {};
  f32x4 oacc[2][4] = {};
  for (int t = 0; t < 8; t++) {
    __syncthreads();
    *(u32x4*)&kb[sr][sc] = rk;
    *(u32x4*)&vtb[sr][sc] = rv;
    __syncthreads();
    if (t < 7) {
      rk = *(const u32x4*)(kb_g + (size_t)(t + 1) * 4096 + (size_t)sr * 64 + sc);
      rv = *(const u32x4*)(vb_g + (size_t)(t + 1) * 64 + (size_t)sr * 4096 + sc);
    }
    // QK^T for both ss halves; kb fragments read once and shared
    f32x4 sa[2][4] = {};
#pragma unroll
    for (int nf = 0; nf < 4; nf++) {
      bf16x8 b0 = lds_frag(&kb[nf * 16 + l15][8 * g]);
      bf16x8 b1 = lds_frag(&kb[nf * 16 + l15][8 * g + 32]);
#pragma unroll
      for (int ss = 0; ss < 2; ss++) {
        sa[ss][nf] = mfma16(aq[ss][0], b0, sa[ss][nf]);
        sa[ss][nf] = mfma16(aq[ss][1], b1, sa[ss][nf]);
      }
    }
    // online softmax for both ss (independent chains -> 2x VALU ILP)
#pragma unroll
    for (int ss = 0; ss < 2; ss++) {
      f32x4 mn, corr;
#pragma unroll
      for (int r = 0; r < 4; r++) {
        float m_ = fmaxf(fmaxf(sa[ss][0][r], sa[ss][1][r]),
                         fmaxf(sa[ss][2][r], sa[ss][3][r]));
#pragma unroll
        for (int msk = 1; msk < 16; msk <<= 1) m_ = fmaxf(m_, __shfl_xor(m_, msk));
        mn[r] = fmaxf(mreg[ss][r], m_);
        corr[r] = __expf(mreg[ss][r] - mn[r]);
        mreg[ss][r] = mn[r];
      }
      f32x4 ps = {};
#pragma unroll
      for (int nf = 0; nf < 4; nf++)
#pragma unroll
        for (int r = 0; r < 4; r++) {
          sa[ss][nf][r] = __expf(sa[ss][nf][r] - mn[r]);
          ps[r] += sa[ss][nf][r];
        }
#pragma unroll
      for (int r = 0; r < 4; r++) {
#pragma unroll
        for (int msk = 1; msk < 16; msk <<= 1) ps[r] += __shfl_xor(ps[r], msk);
        lreg[ss][r] = lreg[ss][r] * corr[r] + ps[r];
      }
#pragma unroll
      for (int nf = 0; nf < 4; nf++) oacc[ss][nf] *= corr;
#pragma unroll
      for (int nf = 0; nf < 4; nf++)
#pragma unroll
        for (int r = 0; r < 4; r++)
          Pb[wv][ss * 16 + 4 * g + r][nf * 16 + l15] = f2b(sa[ss][nf][r]);
    }
    asm volatile("s_waitcnt lgkmcnt(0)" ::: "memory");
    __builtin_amdgcn_sched_barrier(0);
    bf16x8 ap[2][2];
#pragma unroll
    for (int ss = 0; ss < 2; ss++) {
      ap[ss][0] = lds_frag(&Pb[wv][ss * 16 + l15][8 * g]);
      ap[ss][1] = lds_frag(&Pb[wv][ss * 16 + l15][8 * g + 32]);
    }
    // PV for both ss; vtb fragments read once and shared
#pragma unroll
    for (int nf = 0; nf < 4; nf++) {
      bf16x8 b0 = lds_frag(&vtb[nf * 16 + l15][8 * g]);
      bf16x8 b1 = lds_frag(&vtb[nf * 16 + l15][8 * g + 32]);
#pragma unroll
      for (int ss = 0; ss < 2; ss++) {
        oacc[ss][nf] = mfma16(ap[ss][0], b0, oacc[ss][nf]);
        oacc[ss][nf] = mfma16(ap[ss][1], b1, oacc[ss][nf]);
      }
    }
  }
  size_t pb = (size_t)(bh * 8 + kvc) * 64;
#pragma unroll
  for (int ss = 0; ss < 2; ss++) {
    int qbase = wv * 32 + ss * 16;
#pragma unroll
    for (int nf = 0; nf < 4; nf++)
      *(f32x4*)&pacc[(pb + nf * 16 + l15) * 256 + qbase + 4 * g] = oacc[ss][nf];
    if (l15 == 0) {
#pragma unroll
      for (int r = 0; r < 4; r++) {
        size_t mi = ((size_t)(bh * 8 + kvc) * 256 + qbase + 4 * g + r) * 2;
        ml[mi] = mreg[ss][r];
        ml[mi + 1] = lreg[ss][r];
      }
    }
  }
}

// ------- attn3 combine: merge 8 kv-chunk partials -> w3 hi/lo planes -------
__global__ __launch_bounds__(256) void attn3_fin(const float* __restrict__ pacc,
                                                 const float* __restrict__ ml,
                                                 u16* __restrict__ w3h,
                                                 u16* __restrict__ w3l) {
  int dc = blockIdx.x, bh = blockIdx.y;
  int i = threadIdx.x;
  float m[8], l[8], w[8];
  float M = -1e30f;
#pragma unroll
  for (int kv = 0; kv < 8; kv++) {
    size_t mi = ((size_t)(bh * 8 + kv) * 256 + i) * 2;
    m[kv] = ml[mi];
    l[kv] = ml[mi + 1];
    M = fmaxf(M, m[kv]);
  }
  float den = 0.f;
#pragma unroll
  for (int kv = 0; kv < 8; kv++) {
    w[kv] = __expf(m[kv] - M);
    den += w[kv] * l[kv];
  }
  float inv = 1.0f / den;
#pragma unroll
  for (int dd = 0; dd < 16; dd++) {
    int d = dc * 16 + dd;
    float num = 0.f;
#pragma unroll
    for (int kv = 0; kv < 8; kv++)
      num += w[kv] * pacc[((size_t)(bh * 8 + kv) * 64 + d) * 256 + i];
    float val = num * inv;
    u16 hi = f2b(val);
    size_t o = ((size_t)bh * 64 + d) * 256 + i;
    w3h[o] = hi;
    w3l[o] = f2b(val - b2f(hi));
  }
}

// ------- attn1 (MFMA, barrier-free): conv phase hoisted before softmax -------
__global__ __launch_bounds__(256, 4) void attn1_mfma(const u16* __restrict__ q,
                                                     const u16* __restrict__ kF,
                                                     const u16* __restrict__ zwF,
                                                     const u16* __restrict__ vT,
                                                     const float* __restrict__ rker,
                                                     u16* __restrict__ out_h) {
  __shared__ __align__(16) u16 Pl[64][258];
  int tid = threadIdx.x, lane = tid & 63, wv = tid >> 6;
  int l15 = lane & 15, g = lane >> 4;
  int bh = blockIdx.y, h = bh & 7;
  int i0 = blockIdx.x * 64;
  const u16* qp = q + ((size_t)bh * 4096 + i0 + wv * 16 + l15) * 64 + 8 * g;
  bf16x8 aq0 = __builtin_bit_cast(bf16x8, *(const u32x4*)qp);
  bf16x8 aq1 = __builtin_bit_cast(bf16x8, *(const u32x4*)(qp + 32));
  u16 kb16 = (lane < 33) ? f2b(rker[h * 33 + lane]) : (u16)0;
  const u16* kfb = kF + (size_t)bh * 16384 + (size_t)lane * 8;
  f32x4 sacc[16] = {};
#pragma unroll
  for (int nf = 0; nf < 16; nf++) {
    bf16x8 b0 = g_frag(kfb + (nf * 2 + 0) * 512);
    bf16x8 b1 = g_frag(kfb + (nf * 2 + 1) * 512);
    sacc[nf] = mfma16(aq0, b0, sacc[nf]);
    sacc[nf] = mfma16(aq1, b1, sacc[nf]);
  }
  bf16x8 band[2];
#pragma unroll
  for (int ks = 0; ks < 2; ks++) {
    u16 bb[8];
#pragma unroll
    for (int j = 0; j < 8; j++) {
      int idx = 32 * ks + 8 * g + j - l15;
      u16 vsh = (u16)__shfl((int)kb16, idx & 63);
      bb[j] = (idx >= 0 && idx <= 32) ? vsh : (u16)0;
    }
    band[ks] = __builtin_bit_cast(bf16x8, *(u32x4*)bb);
  }
  f32x4 cacc[4] = {};
#pragma unroll
  for (int nf = 0; nf < 4; nf++) {
    int d = nf * 16 + l15;
    const u16* vp = vT + ((size_t)bh * 64 + d) * 4096;
#pragma unroll
    for (int ks = 0; ks < 2; ks++) {
      int col0 = i0 - 16 + 16 * wv + 32 * ks + 8 * g;
      bf16x8 vf;
      if (col0 >= 0 && col0 + 7 < 4096) {
        vf = g_frag(vp + col0);
      } else {
        u16 tmp[8];
#pragma unroll
        for (int j = 0; j < 8; j++) {
          int c = col0 + j;
          tmp[j] = (c >= 0 && c < 4096) ? vp[c] : (u16)0;
        }
        vf = __builtin_bit_cast(bf16x8, *(u32x4*)tmp);
      }
      cacc[nf] = mfma16(band[ks], vf, cacc[nf]);
    }
  }
  f32x4 mx;
#pragma unroll
  for (int r = 0; r < 4; r++) {
    float m_ = sacc[0][r];
#pragma unroll
    for (int nf = 1; nf < 16; nf++) m_ = fmaxf(m_, sacc[nf][r]);
#pragma unroll
    for (int msk = 1; msk < 16; msk <<= 1) m_ = fmaxf(m_, __shfl_xor(m_, msk));
    mx[r] = m_;
  }
  f32x4 ls = {};
#pragma unroll
  for (int nf = 0; nf < 16; nf++)
#pragma unroll
    for (int r = 0; r < 4; r++) {
      sacc[nf][r] = __expf(sacc[nf][r] - mx[r]);
      ls[r] += sacc[nf][r];
    }
  f32x4 invl;
#pragma unroll
  for (int r = 0; r < 4; r++) {
#pragma unroll
    for (int msk = 1; msk < 16; msk <<= 1) ls[r] += __shfl_xor(ls[r], msk);
    invl[r] = 1.0f / ls[r];
  }
#pragma unroll
  for (int nf = 0; nf < 16; nf++)
#pragma unroll
    for (int r = 0; r < 4; r++) Pl[wv * 16 + 4 * g + r][nf * 16 + l15] = f2b(sacc[nf][r]);
  asm volatile("s_waitcnt lgkmcnt(0)" ::: "memory");
  __builtin_amdgcn_sched_barrier(0);
  bf16x8 ap[8];
#pragma unroll
  for (int ks = 0; ks < 8; ks++) ap[ks] = lds_frag(&Pl[wv * 16 + l15][8 * g + 32 * ks]);
  const u16* zfb = zwF + (size_t)bh * 16384 + (size_t)lane * 8;
  f32x4 oacc[4] = {};
#pragma unroll
  for (int nf = 0; nf < 4; nf++) {
#pragma unroll
    for (int ks = 0; ks < 8; ks++) {
      bf16x8 b = g_frag(zfb + (nf * 8 + ks) * 512);
      oacc[nf] = mfma16(ap[ks], b, oacc[nf]);
    }
  }
#pragma unroll
  for (int nf = 0; nf < 4; nf++) {
    int colc = nf * 16 + l15;
#pragma unroll
    for (int r = 0; r < 4; r++) {
      float val = oacc[nf][r] * invl[r] + cacc[nf][r];
      out_h[((size_t)bh * 4096 + i0 + wv * 16 + 4 * g + r) * 64 + colc] = f2b(val);
    }
  }
}

extern "C" void kernel_launch(void* const* d_in, const int* in_sizes, int n_in,
                              void* d_out, int out_size, void* d_ws, size_t ws_size,
                              hipStream_t stream) {
  (void)in_sizes; (void)n_in; (void)out_size;
  const float* x = (const float*)d_in[0];
  const float* w_qkv = (const float*)d_in[1];
  const float* w_out = (const float*)d_in[2];
  const float* b_out = (const float*)d_in[3];
  const float* res_k = (const float*)d_in[4];
  const float* gamma = (const float*)d_in[5];
  const float* beta = (const float*)d_in[6];
  float* out = (float*)d_out;

  char* p = (char*)d_ws;
  auto alloc = [&](size_t bytes) {
    char* r = p;
    p += (bytes + 255) & ~(size_t)255;
    return r;
  };
  const size_t BH = 32;
  const size_t PLANE = BH * 65536 * 2;  // 4.19MB u16 plane [32][256][256]
  const size_t SMALL = BH * 256 * 64 * 2;
  u16* xn = (u16*)alloc(BH * 4096 * 64 * 2);  // aliased: vT after qkv
  u16* vT = xn;
  u16* wTq = (u16*)alloc(1536 * 512 * 2);
  u16* wTo = (u16*)alloc(512 * 512 * 2);
  u16* q = (u16*)alloc(BH * 4096 * 64 * 2);
  u16* k = (u16*)alloc(BH * 4096 * 64 * 2);
  u16* v = (u16*)alloc(BH * 4096 * 64 * 2);
  u16* qlh = (u16*)alloc(SMALL);
  u16* qll = (u16*)alloc(SMALL);
  u16* klh = (u16*)alloc(SMALL);
  u16* kll = (u16*)alloc(SMALL);
  u16* kF = (u16*)alloc(SMALL);
  float* mat = (float*)alloc(BH * 65536 * 4);  // aliased: t4 planes after pinv_init
  u16* t4h = (u16*)mat;
  u16* t4l = t4h + BH * 65536;
  u16* math_ = (u16*)alloc(PLANE);
  u16* matl = (u16*)alloc(PLANE);
  u16* zh = (u16*)alloc(PLANE);
  u16* zl = (u16*)alloc(PLANE);
  u16* zth = (u16*)alloc(PLANE);
  u16* ztl = (u16*)alloc(PLANE);
  char* slotB = alloc(4 * PLANE);  // mz hi/lo + s2 hi/lo; aliased: out_h
  u16* mzh = (u16*)slotB;
  u16* mzl = mzh + BH * 65536;
  u16* s2h = mzl + BH * 65536;
  u16* s2l = s2h + BH * 65536;
  u16* out_h = (u16*)slotB;
  u16* t3h = (u16*)alloc(PLANE);
  u16* t3l = (u16*)alloc(PLANE);
  u16* znh = (u16*)alloc(PLANE);
  u16* znl = (u16*)alloc(PLANE);
  u16* znth = (u16*)alloc(PLANE);
  u16* zntl = (u16*)alloc(PLANE);
  u16* w3h = (u16*)alloc(BH * 64 * 256 * 2);
  u16* w3l = (u16*)alloc(BH * 64 * 256 * 2);
  u16* zwF = (u16*)alloc(BH * 64 * 256 * 2);
  float* colpart = (float*)alloc(256 * 256 * 4);
  float* scal = (float*)alloc(256);
  if ((size_t)(p - (char*)d_ws) > ws_size) return;  // insufficient workspace
  // attn3 partials alias dead NS temporaries
  float* pacc = (float*)t3h;   // [32][8][64][256] f32
  float* mlbuf = (float*)znth; // [32][8][256][2] f32

  hipMemsetAsync(scal, 0, 8, stream);
  ln_k<<<16384, 256, 0, stream>>>(x, gamma, beta, xn);
  transpose_w<<<dim3(24, 8), 256, 0, stream>>>(w_qkv, wTq, 512, 1536);
  transpose_w<<<dim3(8, 8), 256, 0, stream>>>(w_out, wTo, 512, 512);
  gemm_bf16_nt<0><<<dim3(128, 12), 256, 0, stream>>>(xn, wTq, 512, q, k, v, nullptr,
                                                     nullptr, nullptr);
  landmark_mean<<<2048, 256, 0, stream>>>(q, qlh, qll, nullptr);
  landmark_mean<<<2048, 256, 0, stream>>>(k, klh, kll, kF);
  transpose_k<<<dim3(64, 32), 256, 0, stream>>>(v, vT);  // vT aliases xn (xn dead)
  // attn2 logits: mat = q_l @ k_l^T   (K=64, f32 out, hi/lo)
  ns_gemm<1, 1, 64><<<dim3(4, 4, 32), 256, 0, stream>>>(
      qlh, qll, klh, kll, 64, 16384, 16384,
      nullptr, nullptr, nullptr, nullptr, mat, nullptr, 0.f, 1.f, 0.f, 0.f, 0, 0);
  softmax256<<<2048, 256, 0, stream>>>(mat, math_, matl);
  pinv_part<<<256, 256, 0, stream>>>(mat, colpart, scal);
  pinv_fin<<<1, 256, 0, stream>>>(colpart, scal);
  pinv_init<<<8192, 256, 0, stream>>>(mat, scal, zh, zl, zth, ztl);
  u16 *zch = zh, *zcl = zl, *zcth = zth, *zctl = ztl;
  u16 *znh_ = znh, *znl_ = znl, *znth_ = znth, *zntl_ = zntl;
  for (int it = 0; it < 6; it++) {
    dim3 g44(4, 4, 32);
    if (it < 5) {
      // bf16 (hi-only) iterations: NS self-corrects; final iteration refines.
      ns_gemm<0, 0, 128><<<g44, 256, 0, stream>>>(
          math_, matl, zcth, zctl, 256, 65536, 65536,
          mzh, mzl, s2h, s2l, nullptr, nullptr, 0.f, 1.f, 7.f, -1.f, 1, 1);
      ns_gemm<0, 0, 128><<<g44, 256, 0, stream>>>(
          mzh, mzl, s2h, s2l, 256, 65536, 65536,
          nullptr, nullptr, t3h, t3l, nullptr, nullptr, 0.f, 0.f, 15.f, -1.f, 0, 1);
      ns_gemm<0, 0, 128><<<g44, 256, 0, stream>>>(
          mzh, mzl, t3h, t3l, 256, 65536, 65536,
          nullptr, nullptr, t4h, t4l, nullptr, nullptr, 0.f, 0.f, 13.f, -1.f, 0, 1);
      ns_gemm<0, 0, 128><<<g44, 256, 0, stream>>>(
          zch, zcl, t4h, t4l, 256, 65536, 65536,
          znh_, znl_, znth_, zntl_, nullptr, nullptr, 0.f, 0.25f, 0.f, 0.25f, 1, 1);
    } else {
      // final iteration in hi/lo
      ns_gemm<0, 1, 128><<<g44, 256, 0, stream>>>(
          math_, matl, zcth, zctl, 256, 65536, 65536,
          mzh, mzl, s2h, s2l, nullptr, nullptr, 0.f, 1.f, 7.f, -1.f, 1, 1);
      ns_gemm<0, 1, 128><<<g44, 256, 0, stream>>>(
          mzh, mzl, s2h, s2l, 256, 65536, 65536,
          nullptr, nullptr, t3h, t3l, nullptr, nullptr, 0.f, 0.f, 15.f, -1.f, 0, 1);
      ns_gemm<0, 1, 128><<<g44, 256, 0, stream>>>(
          mzh, mzl, t3h, t3l, 256, 65536, 65536,
          nullptr, nullptr, t4h, t4l, nullptr, nullptr, 0.f, 0.f, 13.f, -1.f, 0, 1);
      ns_gemm<0, 1, 128><<<g44, 256, 0, stream>>>(
          zch, zcl, t4h, t4l, 256, 65536, 65536,
          znh_, znl_, znth_, zntl_, nullptr, nullptr, 0.f, 0.25f, 0.f, 0.25f, 1, 1);
    }
    u16* t;
    t = zch; zch = znh_; znh_ = t;
    t = zcl; zcl = znl_; znl_ = t;
    t = zcth; zcth = znth_; znth_ = t;
    t = zctl; zctl = zntl_; zntl_ = t;
  }
  attn3_split<<<dim3(8, 32), 512, 0, stream>>>(qlh, k, vT, pacc, mlbuf);
  attn3_fin<<<dim3(4, 32), 256, 0, stream>>>(pacc, mlbuf, w3h, w3l);
  // zwF = frag-ordered (z @ w3)^T  bf16 (hi/lo)
  ns_gemm<2, 1, 128><<<dim3(4, 1, 32), 256, 0, stream>>>(
      zch, zcl, w3h, w3l, 256, 65536, 16384,
      nullptr, nullptr, nullptr, nullptr, nullptr, zwF, 0.f, 0.f, 0.f, 1.f, 0, 0);
  attn1_mfma<<<dim3(64, 32), 256, 0, stream>>>(q, kF, zwF, vT, res_k, out_h);
  gemm_bf16_nt<1><<<dim3(128, 4), 256, 0, stream>>>(out_h, wTo, 512, nullptr, nullptr,
                                                    nullptr, x, b_out, out);
}

// Round 24
// 467.622 us; speedup vs baseline: 1.0143x; 1.0143x over previous
//
#include <hip/hip_runtime.h>
#include <stdint.h>

#define DEV __device__ __forceinline__

typedef unsigned short u16;
typedef unsigned int u32;
using f32x4 = __attribute__((ext_vector_type(4))) float;
using u32x4 = __attribute__((ext_vector_type(4))) u32;
using bf16x8 = __attribute__((ext_vector_type(8))) __bf16;

DEV float b2f(u16 u) { u32 x = ((u32)u) << 16; return __builtin_bit_cast(float, x); }
DEV u16 f2b(float f) {
  u32 x = __builtin_bit_cast(u32, f);
  return (u16)((x + 0x7FFFu + ((x >> 16) & 1u)) >> 16);
}
DEV u32 pk2(float a, float b) { return (u32)f2b(a) | ((u32)f2b(b) << 16); }
DEV bf16x8 lds_frag(const u16* p) { return __builtin_bit_cast(bf16x8, *(const u32x4*)p); }
DEV bf16x8 g_frag(const u16* p) { return __builtin_bit_cast(bf16x8, *(const u32x4*)p); }
DEV f32x4 mfma16(bf16x8 a, bf16x8 b, f32x4 c) {
  return __builtin_amdgcn_mfma_f32_16x16x32_bf16(a, b, c, 0, 0, 0);
}
DEV float wredmax(float v) {
#pragma unroll
  for (int m = 32; m > 0; m >>= 1) v = fmaxf(v, __shfl_xor(v, m));
  return v;
}
DEV float wredsum(float v) {
#pragma unroll
  for (int m = 32; m > 0; m >>= 1) v += __shfl_xor(v, m);
  return v;
}

// ---------------- LayerNorm: x[16384][512] f32 -> xn bf16 ----------------
__global__ __launch_bounds__(256) void ln_k(const float* __restrict__ x,
                                            const float* __restrict__ gamma,
                                            const float* __restrict__ beta,
                                            u16* __restrict__ xn) {
  int row = blockIdx.x, tid = threadIdx.x;
  int lane = tid & 63, wave = tid >> 6;
  const float* xr = x + (size_t)row * 512;
  float a = xr[2 * tid], b = xr[2 * tid + 1];
  __shared__ float red[8];
  float s = wredsum(a + b);
  if (lane == 0) red[wave] = s;
  __syncthreads();
  float mean = (red[0] + red[1] + red[2] + red[3]) * (1.0f / 512.0f);
  float da = a - mean, db = b - mean;
  float vs = wredsum(da * da + db * db);
  if (lane == 0) red[4 + wave] = vs;
  __syncthreads();
  float var = (red[4] + red[5] + red[6] + red[7]) * (1.0f / 512.0f);
  float rstd = rsqrtf(var + 1e-5f);
  int c = 2 * tid;
  u16 o0 = f2b(da * rstd * gamma[c] + beta[c]);
  u16 o1 = f2b(db * rstd * gamma[c + 1] + beta[c + 1]);
  *(u32*)&xn[(size_t)row * 512 + c] = (u32)o0 | ((u32)o1 << 16);
}

// ------------- transpose f32 [R][C] -> bf16 [C][R] (weights) -------------
__global__ __launch_bounds__(256) void transpose_w(const float* __restrict__ in,
                                                   u16* __restrict__ out, int R, int C) {
  __shared__ float t[64][65];
  int c0 = blockIdx.x * 64, r0 = blockIdx.y * 64;
  int tid = threadIdx.x;
  int r = tid >> 2, cs = (tid & 3) * 16;
  const float* src = in + (size_t)(r0 + r) * C + c0 + cs;
#pragma unroll
  for (int e = 0; e < 16; e++) t[r][cs + e] = src[e];
  __syncthreads();
  int c = tid >> 2, rs = (tid & 3) * 16;
  u16* dst = out + (size_t)(c0 + c) * R + r0 + rs;
#pragma unroll
  for (int e = 0; e < 16; e++) dst[e] = f2b(t[rs + e][c]);
}

// ------------- transpose bf16 src[bh][4096][64] -> dst[bh][64][4096] -------------
__global__ __launch_bounds__(256) void transpose_k(const u16* __restrict__ k,
                                                   u16* __restrict__ kT) {
  __shared__ u16 t[64][72];
  int bh = blockIdx.y, i0 = blockIdx.x * 64;
  int tid = threadIdx.x;
  int r = tid >> 2, ds = (tid & 3) * 16;
  const u16* src = k + (((size_t)bh * 4096) + i0 + r) * 64 + ds;
#pragma unroll
  for (int e = 0; e < 16; e++) t[r][ds + e] = src[e];
  __syncthreads();
  int d = tid >> 2, is = (tid & 3) * 16;
  u16* dst = kT + ((size_t)bh * 64 + d) * 4096 + i0 + is;
#pragma unroll
  for (int e = 0; e < 16; e++) dst[e] = t[is + e][d];
}

// ------------- landmark means -> hi/lo planes + optional frag-ordered hi copy -------------
__global__ __launch_bounds__(256) void landmark_mean(const u16* __restrict__ src,
                                                     u16* __restrict__ dh,
                                                     u16* __restrict__ dl,
                                                     u16* __restrict__ dF) {
  int gid = blockIdx.x * 4 + (threadIdx.x >> 6);
  int lane = threadIdx.x & 63;
  int bh = gid >> 8, lm = gid & 255;
  const u16* p = src + (((size_t)bh * 4096) + lm * 16) * 64 + lane;
  float s = 0.f;
#pragma unroll
  for (int t = 0; t < 16; t++) s += b2f(p[t * 64]);
  float m = s * (1.0f / 16.0f);
  u16 hi = f2b(m);
  size_t idx = ((size_t)bh * 256 + lm) * 64 + lane;
  dh[idx] = hi;
  dl[idx] = f2b(m - b2f(hi));
  if (dF) {
    size_t a = ((((size_t)bh * 16 + (lm >> 4)) * 2 + (lane >> 5)) * 512) +
               (((lane >> 3) & 3) * 128) + ((lm & 15) * 8) + (lane & 7);
    dF[a] = hi;
  }
}

// ---------------- big bf16 NT GEMM: C = A[M][K] * Bt[N][K]^T ----------------
// Direct-store epilogue + register prefetch; BK=64 (8 K-steps for K=512).
template <int MODE>
__global__ __launch_bounds__(256) void gemm_bf16_nt(
    const u16* __restrict__ A, const u16* __restrict__ Bt, int K,
    u16* __restrict__ oq, u16* __restrict__ ok, u16* __restrict__ ov,
    const float* __restrict__ xres, const float* __restrict__ bias,
    float* __restrict__ oc) {
  constexpr int BM = 128, BN = 128, BK = 64, LDT = BK + 8;
  __shared__ __align__(16) u16 Al[BM][LDT];
  __shared__ __align__(16) u16 Bl[BN][LDT];
  int tid = threadIdx.x;
  int lane = tid & 63, wave = tid >> 6;
  int bm = blockIdx.x * BM, bn = blockIdx.y * BN;
  int wm = (wave >> 1) * 64, wn = (wave & 1) * 64;
  int l15 = lane & 15, g = lane >> 4;
  // staging: thread covers rows r and r+64, col chunk c16 (16 u16 = 2 x u32x4)
  int r = tid >> 2, c16 = (tid & 3) * 16;
  auto srcA = [&](int rr, int kc, int kt) -> const u16* {
    if (MODE == 0) return A + (size_t)(bm + rr) * K + kt + kc;
    int m = bm + rr, kk = kt + kc;
    return A + ((((size_t)(m >> 12)) * 8 + (kk >> 6)) * 4096 + (m & 4095)) * 64 + (kk & 63);
  };
  u32x4 a00 = *(const u32x4*)srcA(r, c16, 0);
  u32x4 a01 = *(const u32x4*)(srcA(r, c16, 0) + 8);
  u32x4 a10 = *(const u32x4*)srcA(r + 64, c16, 0);
  u32x4 a11 = *(const u32x4*)(srcA(r + 64, c16, 0) + 8);
  const u16* pb0 = Bt + (size_t)(bn + r) * K + c16;
  const u16* pb1 = Bt + (size_t)(bn + r + 64) * K + c16;
  u32x4 b00 = *(const u32x4*)pb0;
  u32x4 b01 = *(const u32x4*)(pb0 + 8);
  u32x4 b10 = *(const u32x4*)pb1;
  u32x4 b11 = *(const u32x4*)(pb1 + 8);
  f32x4 acc[4][4] = {};
  for (int kt = 0; kt < K; kt += BK) {
    __syncthreads();
    *(u32x4*)&Al[r][c16] = a00;
    *(u32x4*)&Al[r][c16 + 8] = a01;
    *(u32x4*)&Al[r + 64][c16] = a10;
    *(u32x4*)&Al[r + 64][c16 + 8] = a11;
    *(u32x4*)&Bl[r][c16] = b00;
    *(u32x4*)&Bl[r][c16 + 8] = b01;
    *(u32x4*)&Bl[r + 64][c16] = b10;
    *(u32x4*)&Bl[r + 64][c16 + 8] = b11;
    __syncthreads();
    if (kt + BK < K) {
      int kn = kt + BK;
      a00 = *(const u32x4*)srcA(r, c16, kn);
      a01 = *(const u32x4*)(srcA(r, c16, kn) + 8);
      a10 = *(const u32x4*)srcA(r + 64, c16, kn);
      a11 = *(const u32x4*)(srcA(r + 64, c16, kn) + 8);
      b00 = *(const u32x4*)(pb0 + kn);
      b01 = *(const u32x4*)(pb0 + kn + 8);
      b10 = *(const u32x4*)(pb1 + kn);
      b11 = *(const u32x4*)(pb1 + kn + 8);
    }
#pragma unroll
    for (int ks = 0; ks < 2; ks++) {
      int ko = ks * 32 + 8 * g;
      bf16x8 af[4], bf_[4];
#pragma unroll
      for (int i = 0; i < 4; i++) af[i] = lds_frag(&Al[wm + i * 16 + l15][ko]);
#pragma unroll
      for (int i = 0; i < 4; i++) bf_[i] = lds_frag(&Bl[wn + i * 16 + l15][ko]);
#pragma unroll
      for (int mi = 0; mi < 4; mi++)
#pragma unroll
        for (int ni = 0; ni < 4; ni++) acc[mi][ni] = mfma16(af[mi], bf_[ni], acc[mi][ni]);
    }
  }
  if (MODE == 0) {
    int tensor = bn / 512;
    float scale = (tensor == 0) ? 0.125f : 1.0f;
    u16* base = (tensor == 0) ? oq : (tensor == 1 ? ok : ov);
#pragma unroll
    for (int mi = 0; mi < 4; mi++)
#pragma unroll
      for (int ni = 0; ni < 4; ni++) {
        int cw = (bn % 512) + wn + ni * 16 + l15;
        int h = cw >> 6, d = cw & 63;
#pragma unroll
        for (int rr = 0; rr < 4; rr++) {
          int m = bm + wm + mi * 16 + 4 * g + rr;
          int b = m >> 12, i = m & 4095;
          base[(((size_t)(b * 8 + h)) * 4096 + i) * 64 + d] = f2b(acc[mi][ni][rr] * scale);
        }
      }
  } else {
#pragma unroll
    for (int mi = 0; mi < 4; mi++)
#pragma unroll
      for (int ni = 0; ni < 4; ni++) {
        int col = bn + wn + ni * 16 + l15;
#pragma unroll
        for (int rr = 0; rr < 4; rr++) {
          int m = bm + wm + mi * 16 + 4 * g + rr;
          oc[(size_t)m * 512 + col] =
              acc[mi][ni][rr] + xres[(size_t)m * 512 + col] + bias[col];
        }
      }
  }
}

// ---------------- NS-chain GEMM, 64x64 tile, BK=64 (4 barriers/dispatch), padded LDS ----------------
// PREC=1: hi/lo inputs (3 MFMA/product). PREC=0: hi-only (1 MFMA/product).
template <int OMODE, int PREC>
__global__ __launch_bounds__(256) void ns_gemm(
    const u16* __restrict__ Ahg, const u16* __restrict__ Alg,
    const u16* __restrict__ Bhg, const u16* __restrict__ Blg, int K, int sA, int sB,
    u16* __restrict__ Ch, u16* __restrict__ Cl2, u16* __restrict__ Th, u16* __restrict__ Tl,
    float* __restrict__ Cf, u16* __restrict__ Tu,
    float cC, float aC, float cT, float aT, int wrC, int wrT) {
  __shared__ __align__(16) u16 Ahs[64][72], Als[64][72], Bhs[64][72], Bls[64][72];
  int bz = blockIdx.z;
  int tid = threadIdx.x, lane = tid & 63, wave = tid >> 6;
  int l15 = lane & 15, g = lane >> 4;
  int bm = blockIdx.x * 64, bn = blockIdx.y * 64;
  int wm = (wave >> 1) * 32, wn = (wave & 1) * 32;
  const u16* Ah0 = Ahg + (size_t)bz * sA;
  const u16* Al0 = Alg + (size_t)bz * sA;
  const u16* Bh0 = Bhg + (size_t)bz * sB;
  const u16* Bl0 = Blg + (size_t)bz * sB;
  int r = tid >> 2, c16 = (tid & 3) * 16;
  const u16* pa = Ah0 + (size_t)(bm + r) * K + c16;
  const u16* pal = Al0 + (size_t)(bm + r) * K + c16;
  const u16* pb = Bh0 + (size_t)(bn + r) * K + c16;
  const u16* pbl = Bl0 + (size_t)(bn + r) * K + c16;
  u32x4 ra0 = *(const u32x4*)pa, ra1 = *(const u32x4*)(pa + 8);
  u32x4 rc0 = *(const u32x4*)pb, rc1 = *(const u32x4*)(pb + 8);
  u32x4 rb0, rb1, rd0, rd1;
  if (PREC) {
    rb0 = *(const u32x4*)pal;
    rb1 = *(const u32x4*)(pal + 8);
    rd0 = *(const u32x4*)pbl;
    rd1 = *(const u32x4*)(pbl + 8);
  }
  f32x4 acc[2][2] = {};
  int nt = K >> 6;
  for (int t = 0; t < nt; t++) {
    __syncthreads();
    *(u32x4*)&Ahs[r][c16] = ra0;
    *(u32x4*)&Ahs[r][c16 + 8] = ra1;
    *(u32x4*)&Bhs[r][c16] = rc0;
    *(u32x4*)&Bhs[r][c16 + 8] = rc1;
    if (PREC) {
      *(u32x4*)&Als[r][c16] = rb0;
      *(u32x4*)&Als[r][c16 + 8] = rb1;
      *(u32x4*)&Bls[r][c16] = rd0;
      *(u32x4*)&Bls[r][c16 + 8] = rd1;
    }
    __syncthreads();
    if (t + 1 < nt) {
      int kt = (t + 1) << 6;
      ra0 = *(const u32x4*)(pa + kt);
      ra1 = *(const u32x4*)(pa + kt + 8);
      rc0 = *(const u32x4*)(pb + kt);
      rc1 = *(const u32x4*)(pb + kt + 8);
      if (PREC) {
        rb0 = *(const u32x4*)(pal + kt);
        rb1 = *(const u32x4*)(pal + kt + 8);
        rd0 = *(const u32x4*)(pbl + kt);
        rd1 = *(const u32x4*)(pbl + kt + 8);
      }
    }
#pragma unroll
    for (int ks = 0; ks < 2; ks++) {
      int ko = ks * 32 + 8 * g;
      bf16x8 ah[2], al[2], bh_[2], bl_[2];
#pragma unroll
      for (int i = 0; i < 2; i++) {
        int ro = wm + i * 16 + l15;
        int rn = wn + i * 16 + l15;
        ah[i] = lds_frag(&Ahs[ro][ko]);
        bh_[i] = lds_frag(&Bhs[rn][ko]);
        if (PREC) {
          al[i] = lds_frag(&Als[ro][ko]);
          bl_[i] = lds_frag(&Bls[rn][ko]);
        }
      }
#pragma unroll
      for (int mi = 0; mi < 2; mi++)
#pragma unroll
        for (int ni = 0; ni < 2; ni++) {
          acc[mi][ni] = mfma16(ah[mi], bh_[ni], acc[mi][ni]);
          if (PREC) {
            acc[mi][ni] = mfma16(ah[mi], bl_[ni], acc[mi][ni]);
            acc[mi][ni] = mfma16(al[mi], bh_[ni], acc[mi][ni]);
          }
        }
    }
  }
#pragma unroll
  for (int mi = 0; mi < 2; mi++)
#pragma unroll
    for (int ni = 0; ni < 2; ni++) {
      int r0 = bm + wm + mi * 16 + 4 * g;
      int cg = bn + wn + ni * 16 + l15;
      f32x4 a = acc[mi][ni];
      if (OMODE == 1) {
        float* c = Cf + (size_t)bz * 65536;
#pragma unroll
        for (int rr = 0; rr < 4; rr++)
          c[(size_t)(r0 + rr) * 256 + cg] = aC * a[rr] + ((r0 + rr) == cg ? cC : 0.f);
      } else if (OMODE == 2) {
        u16 pp[4];
#pragma unroll
        for (int rr = 0; rr < 4; rr++) pp[rr] = f2b(aT * a[rr]);
        u16* tp = Tu + ((((size_t)bz * 4 + (cg >> 4)) * 8 + (r0 >> 5)) * 512) +
                  (((r0 >> 3) & 3) * 128) + ((cg & 15) * 8) + (r0 & 7);
        *(u32*)tp = (u32)pp[0] | ((u32)pp[1] << 16);
        *(u32*)(tp + 2) = (u32)pp[2] | ((u32)pp[3] << 16);
      } else {
        if (wrC) {
#pragma unroll
          for (int rr = 0; rr < 4; rr++) {
            float v = aC * a[rr] + ((r0 + rr) == cg ? cC : 0.f);
            u16 hi = f2b(v);
            size_t idx = (size_t)bz * 65536 + (size_t)(r0 + rr) * 256 + cg;
            Ch[idx] = hi;
            Cl2[idx] = f2b(v - b2f(hi));
          }
        }
        if (wrT) {
          u16 ph[4], pl[4];
#pragma unroll
          for (int rr = 0; rr < 4; rr++) {
            float v = aT * a[rr] + ((r0 + rr) == cg ? cT : 0.f);
            ph[rr] = f2b(v);
            pl[rr] = f2b(v - b2f(ph[rr]));
          }
          size_t idx = (size_t)bz * 65536 + (size_t)cg * 256 + r0;
          *(u32*)&Th[idx] = (u32)ph[0] | ((u32)ph[1] << 16);
          *(u32*)&Th[idx + 2] = (u32)ph[2] | ((u32)ph[3] << 16);
          *(u32*)&Tl[idx] = (u32)pl[0] | ((u32)pl[1] << 16);
          *(u32*)&Tl[idx + 2] = (u32)pl[2] | ((u32)pl[3] << 16);
        }
      }
    }
}

// ---------------- row softmax over 256 (in place) + hi/lo plane output ----------------
__global__ __launch_bounds__(256) void softmax256(float* __restrict__ S,
                                                  u16* __restrict__ Sh,
                                                  u16* __restrict__ Sl) {
  int row = blockIdx.x * 4 + (threadIdx.x >> 6);
  int lane = threadIdx.x & 63;
  float* r = S + (size_t)row * 256;
  f32x4 vv = *(f32x4*)&r[lane * 4];
  float mx = wredmax(fmaxf(fmaxf(vv[0], vv[1]), fmaxf(vv[2], vv[3])));
  vv[0] = __expf(vv[0] - mx);
  vv[1] = __expf(vv[1] - mx);
  vv[2] = __expf(vv[2] - mx);
  vv[3] = __expf(vv[3] - mx);
  float sm = wredsum(vv[0] + vv[1] + vv[2] + vv[3]);
  vv *= (1.0f / sm);
  *(f32x4*)&r[lane * 4] = vv;
  u16 h[4], l[4];
#pragma unroll
  for (int e = 0; e < 4; e++) {
    h[e] = f2b(vv[e]);
    l[e] = f2b(vv[e] - b2f(h[e]));
  }
  size_t p = (size_t)row * 256 + lane * 4;
  *(u32*)&Sh[p] = (u32)h[0] | ((u32)h[1] << 16);
  *(u32*)&Sh[p + 2] = (u32)h[2] | ((u32)h[3] << 16);
  *(u32*)&Sl[p] = (u32)l[0] | ((u32)l[1] << 16);
  *(u32*)&Sl[p + 2] = (u32)l[2] | ((u32)l[3] << 16);
}

// ---------------- pinv scale, stage 1 ----------------
__global__ __launch_bounds__(256) void pinv_part(const float* __restrict__ mat,
                                                 float* __restrict__ colpart,
                                                 float* __restrict__ scal) {
  int blk = blockIdx.x;
  int bh = blk >> 3, ch = blk & 7;
  const float* m = mat + (size_t)bh * 65536 + (size_t)ch * 32 * 256;
  int tid = threadIdx.x, lane = tid & 63, wv = tid >> 6;
  float cp = 0.f;
#pragma unroll 4
  for (int r2 = 0; r2 < 32; r2++) cp += m[r2 * 256 + tid];
  colpart[(size_t)blk * 256 + tid] = cp;
  float rmax = 0.f;
#pragma unroll
  for (int rr = 0; rr < 8; rr++) {
    f32x4 v = *(const f32x4*)&m[(wv * 8 + rr) * 256 + lane * 4];
    float s = wredsum(v[0] + v[1] + v[2] + v[3]);
    rmax = fmaxf(rmax, s);
  }
  if (lane == 0) atomicMax((int*)&scal[1], __float_as_int(rmax));
}

// ---------------- pinv scale, stage 2 ----------------
__global__ __launch_bounds__(256) void pinv_fin(const float* __restrict__ colpart,
                                                float* __restrict__ scal) {
  int tid = threadIdx.x;
  float mx = 0.f;
  for (int bh = 0; bh < 32; bh++) {
    float s = 0.f;
#pragma unroll
    for (int ch = 0; ch < 8; ch++) s += colpart[((size_t)bh * 8 + ch) * 256 + tid];
    mx = fmaxf(mx, s);
  }
  mx = wredmax(mx);
  __shared__ float red[4];
  if ((tid & 63) == 0) red[tid >> 6] = mx;
  __syncthreads();
  if (tid == 0) {
    float a = fmaxf(fmaxf(red[0], red[1]), fmaxf(red[2], red[3]));
    atomicMax((int*)&scal[0], __float_as_int(a));
  }
}

// ---------------- pinv init: z = matT*s, zT = mat*s  (hi/lo planes) ----------------
__global__ __launch_bounds__(256) void pinv_init(const float* __restrict__ mat,
                                                 const float* __restrict__ scal,
                                                 u16* __restrict__ zh, u16* __restrict__ zl,
                                                 u16* __restrict__ zth, u16* __restrict__ ztl) {
  size_t idx = (size_t)blockIdx.x * 256 + threadIdx.x;
  int bh = (int)(idx >> 16);
  int i = (int)((idx >> 8) & 255), j = (int)(idx & 255);
  float s = 1.0f / (scal[0] * scal[1]);
  float val = mat[idx] * s;
  u16 hi = f2b(val);
  u16 lo = f2b(val - b2f(hi));
  zth[idx] = hi;
  ztl[idx] = lo;
  size_t tixd = ((size_t)bh << 16) + ((size_t)j << 8) + i;
  zh[tixd] = hi;
  zl[tixd] = lo;
}

// ------- attn3 split-KV flash v3: merged ss chains (2x ILP, one LDS round-trip/tile) -------
__global__ __launch_bounds__(512) void attn3_split(const u16* __restrict__ qlh,
                                                   const u16* __restrict__ k,
                                                   const u16* __restrict__ vT,
                                                   float* __restrict__ pacc,
                                                   float* __restrict__ ml) {
  __shared__ __align__(16) u16 kb[64][72];
  __shared__ __align__(16) u16 vtb[64][72];
  __shared__ __align__(16) u16 Pb[8][32][72];
  int tid = threadIdx.x, lane = tid & 63, wv = tid >> 6;
  int l15 = lane & 15, g = lane >> 4;
  int bh = blockIdx.y, kvc = blockIdx.x;
  const u16* kb_g = k + ((size_t)bh * 4096 + (size_t)kvc * 512) * 64;
  const u16* vb_g = vT + (size_t)bh * 64 * 4096 + (size_t)kvc * 512;
  bf16x8 aq[2][2];
#pragma unroll
  for (int ss = 0; ss < 2; ss++) {
    const u16* qlp = qlh + ((size_t)bh * 256 + wv * 32 + ss * 16 + l15) * 64 + 8 * g;
    aq[ss][0] = g_frag(qlp);
    aq[ss][1] = g_frag(qlp + 32);
  }
  int sr = tid >> 3, sc = (tid & 7) * 8;
  u32x4 rk = *(const u32x4*)(kb_g + (size_t)sr * 64 + sc);
  u32x4 rv = *(const u32x4*)(vb_g + (size_t)sr * 4096 + sc);
  f32x4 minit = {-1e30f, -1e30f, -1e30f, -1e30f};
  f32x4 mreg[2] = {minit, minit};
  f32x4 lreg[2] = {};
  f32x4 oacc[2][4] = {};
  for (int t = 0; t < 8; t++) {
    __syncthreads();
    *(u32x4*)&kb[sr][sc] = rk;
    *(u32x4*)&vtb[sr][sc] = rv;
    __syncthreads();
    if (t < 7) {
      rk = *(const u32x4*)(kb_g + (size_t)(t + 1) * 4096 + (size_t)sr * 64 + sc);
      rv = *(const u32x4*)(vb_g + (size_t)(t + 1) * 64 + (size_t)sr * 4096 + sc);
    }
    // QK^T for both ss halves; kb fragments read once and shared
    f32x4 sa[2][4] = {};
#pragma unroll
    for (int nf = 0; nf < 4; nf++) {
      bf16x8 b0 = lds_frag(&kb[nf * 16 + l15][8 * g]);
      bf16x8 b1 = lds_frag(&kb[nf * 16 + l15][8 * g + 32]);
#pragma unroll
      for (int ss = 0; ss < 2; ss++) {
        sa[ss][nf] = mfma16(aq[ss][0], b0, sa[ss][nf]);
        sa[ss][nf] = mfma16(aq[ss][1], b1, sa[ss][nf]);
      }
    }
    // online softmax for both ss (independent chains -> 2x VALU ILP)
#pragma unroll
    for (int ss = 0; ss < 2; ss++) {
      f32x4 mn, corr;
#pragma unroll
      for (int r = 0; r < 4; r++) {
        float m_ = fmaxf(fmaxf(sa[ss][0][r], sa[ss][1][r]),
                         fmaxf(sa[ss][2][r], sa[ss][3][r]));
#pragma unroll
        for (int msk = 1; msk < 16; msk <<= 1) m_ = fmaxf(m_, __shfl_xor(m_, msk));
        mn[r] = fmaxf(mreg[ss][r], m_);
        corr[r] = __expf(mreg[ss][r] - mn[r]);
        mreg[ss][r] = mn[r];
      }
      f32x4 ps = {};
#pragma unroll
      for (int nf = 0; nf < 4; nf++)
#pragma unroll
        for (int r = 0; r < 4; r++) {
          sa[ss][nf][r] = __expf(sa[ss][nf][r] - mn[r]);
          ps[r] += sa[ss][nf][r];
        }
#pragma unroll
      for (int r = 0; r < 4; r++) {
#pragma unroll
        for (int msk = 1; msk < 16; msk <<= 1) ps[r] += __shfl_xor(ps[r], msk);
        lreg[ss][r] = lreg[ss][r] * corr[r] + ps[r];
      }
#pragma unroll
      for (int nf = 0; nf < 4; nf++) oacc[ss][nf] *= corr;
#pragma unroll
      for (int nf = 0; nf < 4; nf++)
#pragma unroll
        for (int r = 0; r < 4; r++)
          Pb[wv][ss * 16 + 4 * g + r][nf * 16 + l15] = f2b(sa[ss][nf][r]);
    }
    asm volatile("s_waitcnt lgkmcnt(0)" ::: "memory");
    __builtin_amdgcn_sched_barrier(0);
    bf16x8 ap[2][2];
#pragma unroll
    for (int ss = 0; ss < 2; ss++) {
      ap[ss][0] = lds_frag(&Pb[wv][ss * 16 + l15][8 * g]);
      ap[ss][1] = lds_frag(&Pb[wv][ss * 16 + l15][8 * g + 32]);
    }
    // PV for both ss; vtb fragments read once and shared
#pragma unroll
    for (int nf = 0; nf < 4; nf++) {
      bf16x8 b0 = lds_frag(&vtb[nf * 16 + l15][8 * g]);
      bf16x8 b1 = lds_frag(&vtb[nf * 16 + l15][8 * g + 32]);
#pragma unroll
      for (int ss = 0; ss < 2; ss++) {
        oacc[ss][nf] = mfma16(ap[ss][0], b0, oacc[ss][nf]);
        oacc[ss][nf] = mfma16(ap[ss][1], b1, oacc[ss][nf]);
      }
    }
  }
  size_t pb = (size_t)(bh * 8 + kvc) * 64;
#pragma unroll
  for (int ss = 0; ss < 2; ss++) {
    int qbase = wv * 32 + ss * 16;
#pragma unroll
    for (int nf = 0; nf < 4; nf++)
      *(f32x4*)&pacc[(pb + nf * 16 + l15) * 256 + qbase + 4 * g] = oacc[ss][nf];
    if (l15 == 0) {
#pragma unroll
      for (int r = 0; r < 4; r++) {
        size_t mi = ((size_t)(bh * 8 + kvc) * 256 + qbase + 4 * g + r) * 2;
        ml[mi] = mreg[ss][r];
        ml[mi + 1] = lreg[ss][r];
      }
    }
  }
}

// ------- attn3 combine: merge 8 kv-chunk partials -> w3 hi/lo planes -------
__global__ __launch_bounds__(256) void attn3_fin(const float* __restrict__ pacc,
                                                 const float* __restrict__ ml,
                                                 u16* __restrict__ w3h,
                                                 u16* __restrict__ w3l) {
  int dc = blockIdx.x, bh = blockIdx.y;
  int i = threadIdx.x;
  float m[8], l[8], w[8];
  float M = -1e30f;
#pragma unroll
  for (int kv = 0; kv < 8; kv++) {
    size_t mi = ((size_t)(bh * 8 + kv) * 256 + i) * 2;
    m[kv] = ml[mi];
    l[kv] = ml[mi + 1];
    M = fmaxf(M, m[kv]);
  }
  float den = 0.f;
#pragma unroll
  for (int kv = 0; kv < 8; kv++) {
    w[kv] = __expf(m[kv] - M);
    den += w[kv] * l[kv];
  }
  float inv = 1.0f / den;
#pragma unroll
  for (int dd = 0; dd < 16; dd++) {
    int d = dc * 16 + dd;
    float num = 0.f;
#pragma unroll
    for (int kv = 0; kv < 8; kv++)
      num += w[kv] * pacc[((size_t)(bh * 8 + kv) * 64 + d) * 256 + i];
    float val = num * inv;
    u16 hi = f2b(val);
    size_t o = ((size_t)bh * 64 + d) * 256 + i;
    w3h[o] = hi;
    w3l[o] = f2b(val - b2f(hi));
  }
}

// ------- attn1 (MFMA, barrier-free): conv phase hoisted before softmax -------
__global__ __launch_bounds__(256, 4) void attn1_mfma(const u16* __restrict__ q,
                                                     const u16* __restrict__ kF,
                                                     const u16* __restrict__ zwF,
                                                     const u16* __restrict__ vT,
                                                     const float* __restrict__ rker,
                                                     u16* __restrict__ out_h) {
  __shared__ __align__(16) u16 Pl[64][258];
  int tid = threadIdx.x, lane = tid & 63, wv = tid >> 6;
  int l15 = lane & 15, g = lane >> 4;
  int bh = blockIdx.y, h = bh & 7;
  int i0 = blockIdx.x * 64;
  const u16* qp = q + ((size_t)bh * 4096 + i0 + wv * 16 + l15) * 64 + 8 * g;
  bf16x8 aq0 = __builtin_bit_cast(bf16x8, *(const u32x4*)qp);
  bf16x8 aq1 = __builtin_bit_cast(bf16x8, *(const u32x4*)(qp + 32));
  u16 kb16 = (lane < 33) ? f2b(rker[h * 33 + lane]) : (u16)0;
  const u16* kfb = kF + (size_t)bh * 16384 + (size_t)lane * 8;
  f32x4 sacc[16] = {};
#pragma unroll
  for (int nf = 0; nf < 16; nf++) {
    bf16x8 b0 = g_frag(kfb + (nf * 2 + 0) * 512);
    bf16x8 b1 = g_frag(kfb + (nf * 2 + 1) * 512);
    sacc[nf] = mfma16(aq0, b0, sacc[nf]);
    sacc[nf] = mfma16(aq1, b1, sacc[nf]);
  }
  bf16x8 band[2];
#pragma unroll
  for (int ks = 0; ks < 2; ks++) {
    u16 bb[8];
#pragma unroll
    for (int j = 0; j < 8; j++) {
      int idx = 32 * ks + 8 * g + j - l15;
      u16 vsh = (u16)__shfl((int)kb16, idx & 63);
      bb[j] = (idx >= 0 && idx <= 32) ? vsh : (u16)0;
    }
    band[ks] = __builtin_bit_cast(bf16x8, *(u32x4*)bb);
  }
  f32x4 cacc[4] = {};
#pragma unroll
  for (int nf = 0; nf < 4; nf++) {
    int d = nf * 16 + l15;
    const u16* vp = vT + ((size_t)bh * 64 + d) * 4096;
#pragma unroll
    for (int ks = 0; ks < 2; ks++) {
      int col0 = i0 - 16 + 16 * wv + 32 * ks + 8 * g;
      bf16x8 vf;
      if (col0 >= 0 && col0 + 7 < 4096) {
        vf = g_frag(vp + col0);
      } else {
        u16 tmp[8];
#pragma unroll
        for (int j = 0; j < 8; j++) {
          int c = col0 + j;
          tmp[j] = (c >= 0 && c < 4096) ? vp[c] : (u16)0;
        }
        vf = __builtin_bit_cast(bf16x8, *(u32x4*)tmp);
      }
      cacc[nf] = mfma16(band[ks], vf, cacc[nf]);
    }
  }
  f32x4 mx;
#pragma unroll
  for (int r = 0; r < 4; r++) {
    float m_ = sacc[0][r];
#pragma unroll
    for (int nf = 1; nf < 16; nf++) m_ = fmaxf(m_, sacc[nf][r]);
#pragma unroll
    for (int msk = 1; msk < 16; msk <<= 1) m_ = fmaxf(m_, __shfl_xor(m_, msk));
    mx[r] = m_;
  }
  f32x4 ls = {};
#pragma unroll
  for (int nf = 0; nf < 16; nf++)
#pragma unroll
    for (int r = 0; r < 4; r++) {
      sacc[nf][r] = __expf(sacc[nf][r] - mx[r]);
      ls[r] += sacc[nf][r];
    }
  f32x4 invl;
#pragma unroll
  for (int r = 0; r < 4; r++) {
#pragma unroll
    for (int msk = 1; msk < 16; msk <<= 1) ls[r] += __shfl_xor(ls[r], msk);
    invl[r] = 1.0f / ls[r];
  }
#pragma unroll
  for (int nf = 0; nf < 16; nf++)
#pragma unroll
    for (int r = 0; r < 4; r++) Pl[wv * 16 + 4 * g + r][nf * 16 + l15] = f2b(sacc[nf][r]);
  asm volatile("s_waitcnt lgkmcnt(0)" ::: "memory");
  __builtin_amdgcn_sched_barrier(0);
  bf16x8 ap[8];
#pragma unroll
  for (int ks = 0; ks < 8; ks++) ap[ks] = lds_frag(&Pl[wv * 16 + l15][8 * g + 32 * ks]);
  const u16* zfb = zwF + (size_t)bh * 16384 + (size_t)lane * 8;
  f32x4 oacc[4] = {};
#pragma unroll
  for (int nf = 0; nf < 4; nf++) {
#pragma unroll
    for (int ks = 0; ks < 8; ks++) {
      bf16x8 b = g_frag(zfb + (nf * 8 + ks) * 512);
      oacc[nf] = mfma16(ap[ks], b, oacc[nf]);
    }
  }
#pragma unroll
  for (int nf = 0; nf < 4; nf++) {
    int colc = nf * 16 + l15;
#pragma unroll
    for (int r = 0; r < 4; r++) {
      float val = oacc[nf][r] * invl[r] + cacc[nf][r];
      out_h[((size_t)bh * 4096 + i0 + wv * 16 + 4 * g + r) * 64 + colc] = f2b(val);
    }
  }
}

extern "C" void kernel_launch(void* const* d_in, const int* in_sizes, int n_in,
                              void* d_out, int out_size, void* d_ws, size_t ws_size,
                              hipStream_t stream) {
  (void)in_sizes; (void)n_in; (void)out_size;
  const float* x = (const float*)d_in[0];
  const float* w_qkv = (const float*)d_in[1];
  const float* w_out = (const float*)d_in[2];
  const float* b_out = (const float*)d_in[3];
  const float* res_k = (const float*)d_in[4];
  const float* gamma = (const float*)d_in[5];
  const float* beta = (const float*)d_in[6];
  float* out = (float*)d_out;

  char* p = (char*)d_ws;
  auto alloc = [&](size_t bytes) {
    char* r = p;
    p += (bytes + 255) & ~(size_t)255;
    return r;
  };
  const size_t BH = 32;
  const size_t PLANE = BH * 65536 * 2;  // 4.19MB u16 plane [32][256][256]
  const size_t SMALL = BH * 256 * 64 * 2;
  u16* xn = (u16*)alloc(BH * 4096 * 64 * 2);  // aliased: vT after qkv
  u16* vT = xn;
  u16* wTq = (u16*)alloc(1536 * 512 * 2);
  u16* wTo = (u16*)alloc(512 * 512 * 2);
  u16* q = (u16*)alloc(BH * 4096 * 64 * 2);
  u16* k = (u16*)alloc(BH * 4096 * 64 * 2);
  u16* v = (u16*)alloc(BH * 4096 * 64 * 2);
  u16* qlh = (u16*)alloc(SMALL);
  u16* qll = (u16*)alloc(SMALL);
  u16* klh = (u16*)alloc(SMALL);
  u16* kll = (u16*)alloc(SMALL);
  u16* kF = (u16*)alloc(SMALL);
  float* mat = (float*)alloc(BH * 65536 * 4);  // aliased: t4 planes after pinv_init
  u16* t4h = (u16*)mat;
  u16* t4l = t4h + BH * 65536;
  u16* math_ = (u16*)alloc(PLANE);
  u16* matl = (u16*)alloc(PLANE);
  u16* zh = (u16*)alloc(PLANE);
  u16* zl = (u16*)alloc(PLANE);
  u16* zth = (u16*)alloc(PLANE);
  u16* ztl = (u16*)alloc(PLANE);
  char* slotB = alloc(4 * PLANE);  // mz hi/lo + s2 hi/lo; aliased: out_h
  u16* mzh = (u16*)slotB;
  u16* mzl = mzh + BH * 65536;
  u16* s2h = mzl + BH * 65536;
  u16* s2l = s2h + BH * 65536;
  u16* out_h = (u16*)slotB;
  u16* t3h = (u16*)alloc(PLANE);
  u16* t3l = (u16*)alloc(PLANE);
  u16* znh = (u16*)alloc(PLANE);
  u16* znl = (u16*)alloc(PLANE);
  u16* znth = (u16*)alloc(PLANE);
  u16* zntl = (u16*)alloc(PLANE);
  u16* w3h = (u16*)alloc(BH * 64 * 256 * 2);
  u16* w3l = (u16*)alloc(BH * 64 * 256 * 2);
  u16* zwF = (u16*)alloc(BH * 64 * 256 * 2);
  float* colpart = (float*)alloc(256 * 256 * 4);
  float* scal = (float*)alloc(256);
  if ((size_t)(p - (char*)d_ws) > ws_size) return;  // insufficient workspace
  // attn3 partials alias dead NS temporaries
  float* pacc = (float*)t3h;   // [32][8][64][256] f32
  float* mlbuf = (float*)znth; // [32][8][256][2] f32

  hipMemsetAsync(scal, 0, 8, stream);
  ln_k<<<16384, 256, 0, stream>>>(x, gamma, beta, xn);
  transpose_w<<<dim3(24, 8), 256, 0, stream>>>(w_qkv, wTq, 512, 1536);
  transpose_w<<<dim3(8, 8), 256, 0, stream>>>(w_out, wTo, 512, 512);
  gemm_bf16_nt<0><<<dim3(128, 12), 256, 0, stream>>>(xn, wTq, 512, q, k, v, nullptr,
                                                     nullptr, nullptr);
  landmark_mean<<<2048, 256, 0, stream>>>(q, qlh, qll, nullptr);
  landmark_mean<<<2048, 256, 0, stream>>>(k, klh, kll, kF);
  transpose_k<<<dim3(64, 32), 256, 0, stream>>>(v, vT);  // vT aliases xn (xn dead)
  // attn2 logits: mat = q_l @ k_l^T   (K=64, f32 out, hi/lo)
  ns_gemm<1, 1><<<dim3(4, 4, 32), 256, 0, stream>>>(
      qlh, qll, klh, kll, 64, 16384, 16384,
      nullptr, nullptr, nullptr, nullptr, mat, nullptr, 0.f, 1.f, 0.f, 0.f, 0, 0);
  softmax256<<<2048, 256, 0, stream>>>(mat, math_, matl);
  pinv_part<<<256, 256, 0, stream>>>(mat, colpart, scal);
  pinv_fin<<<1, 256, 0, stream>>>(colpart, scal);
  pinv_init<<<8192, 256, 0, stream>>>(mat, scal, zh, zl, zth, ztl);
  u16 *zch = zh, *zcl = zl, *zcth = zth, *zctl = ztl;
  u16 *znh_ = znh, *znl_ = znl, *znth_ = znth, *zntl_ = zntl;
  for (int it = 0; it < 6; it++) {
    dim3 g44(4, 4, 32);
    if (it < 5) {
      // bf16 (hi-only) iterations: NS self-corrects; final iteration refines.
      ns_gemm<0, 0><<<g44, 256, 0, stream>>>(
          math_, matl, zcth, zctl, 256, 65536, 65536,
          mzh, mzl, s2h, s2l, nullptr, nullptr, 0.f, 1.f, 7.f, -1.f, 1, 1);
      ns_gemm<0, 0><<<g44, 256, 0, stream>>>(
          mzh, mzl, s2h, s2l, 256, 65536, 65536,
          nullptr, nullptr, t3h, t3l, nullptr, nullptr, 0.f, 0.f, 15.f, -1.f, 0, 1);
      ns_gemm<0, 0><<<g44, 256, 0, stream>>>(
          mzh, mzl, t3h, t3l, 256, 65536, 65536,
          nullptr, nullptr, t4h, t4l, nullptr, nullptr, 0.f, 0.f, 13.f, -1.f, 0, 1);
      ns_gemm<0, 0><<<g44, 256, 0, stream>>>(
          zch, zcl, t4h, t4l, 256, 65536, 65536,
          znh_, znl_, znth_, zntl_, nullptr, nullptr, 0.f, 0.25f, 0.f, 0.25f, 1, 1);
    } else {
      // final iteration in hi/lo
      ns_gemm<0, 1><<<g44, 256, 0, stream>>>(
          math_, matl, zcth, zctl, 256, 65536, 65536,
          mzh, mzl, s2h, s2l, nullptr, nullptr, 0.f, 1.f, 7.f, -1.f, 1, 1);
      ns_gemm<0, 1><<<g44, 256, 0, stream>>>(
          mzh, mzl, s2h, s2l, 256, 65536, 65536,
          nullptr, nullptr, t3h, t3l, nullptr, nullptr, 0.f, 0.f, 15.f, -1.f, 0, 1);
      ns_gemm<0, 1><<<g44, 256, 0, stream>>>(
          mzh, mzl, t3h, t3l, 256, 65536, 65536,
          nullptr, nullptr, t4h, t4l, nullptr, nullptr, 0.f, 0.f, 13.f, -1.f, 0, 1);
      ns_gemm<0, 1><<<g44, 256, 0, stream>>>(
          zch, zcl, t4h, t4l, 256, 65536, 65536,
          znh_, znl_, znth_, zntl_, nullptr, nullptr, 0.f, 0.25f, 0.f, 0.25f, 1, 1);
    }
    u16* t;
    t = zch; zch = znh_; znh_ = t;
    t = zcl; zcl = znl_; znl_ = t;
    t = zcth; zcth = znth_; znth_ = t;
    t = zctl; zctl = zntl_; zntl_ = t;
  }
  attn3_split<<<dim3(8, 32), 512, 0, stream>>>(qlh, k, vT, pacc, mlbuf);
  attn3_fin<<<dim3(4, 32), 256, 0, stream>>>(pacc, mlbuf, w3h, w3l);
  // zwF = frag-ordered (z @ w3)^T  bf16 (hi/lo)
  ns_gemm<2, 1><<<dim3(4, 1, 32), 256, 0, stream>>>(
      zch, zcl, w3h, w3l, 256, 65536, 16384,
      nullptr, nullptr, nullptr, nullptr, nullptr, zwF, 0.f, 0.f, 0.f, 1.f, 0, 0);
  attn1_mfma<<<dim3(64, 32), 256, 0, stream>>>(q, kF, zwF, vT, res_k, out_h);
  gemm_bf16_nt<1><<<dim3(128, 4), 256, 0, stream>>>(out_h, wTo, 512, nullptr, nullptr,
                                                    nullptr, x, b_out, out);
}

// Round 25
// 436.827 us; speedup vs baseline: 1.0858x; 1.0705x over previous
//
#include <hip/hip_runtime.h>
#include <stdint.h>

#define DEV __device__ __forceinline__

typedef unsigned short u16;
typedef unsigned int u32;
using f32x4 = __attribute__((ext_vector_type(4))) float;
using u32x4 = __attribute__((ext_vector_type(4))) u32;
using bf16x8 = __attribute__((ext_vector_type(8))) __bf16;

DEV float b2f(u16 u) { u32 x = ((u32)u) << 16; return __builtin_bit_cast(float, x); }
DEV u16 f2b(float f) {
  u32 x = __builtin_bit_cast(u32, f);
  return (u16)((x + 0x7FFFu + ((x >> 16) & 1u)) >> 16);
}
DEV u32 pk2(float a, float b) { return (u32)f2b(a) | ((u32)f2b(b) << 16); }
DEV bf16x8 lds_frag(const u16* p) { return __builtin_bit_cast(bf16x8, *(const u32x4*)p); }
DEV bf16x8 g_frag(const u16* p) { return __builtin_bit_cast(bf16x8, *(const u32x4*)p); }
DEV f32x4 mfma16(bf16x8 a, bf16x8 b, f32x4 c) {
  return __builtin_amdgcn_mfma_f32_16x16x32_bf16(a, b, c, 0, 0, 0);
}
DEV float wredmax(float v) {
#pragma unroll
  for (int m = 32; m > 0; m >>= 1) v = fmaxf(v, __shfl_xor(v, m));
  return v;
}
DEV float wredsum(float v) {
#pragma unroll
  for (int m = 32; m > 0; m >>= 1) v += __shfl_xor(v, m);
  return v;
}

// ---------------- LayerNorm: x[16384][512] f32 -> xn bf16 ----------------
__global__ __launch_bounds__(256) void ln_k(const float* __restrict__ x,
                                            const float* __restrict__ gamma,
                                            const float* __restrict__ beta,
                                            u16* __restrict__ xn) {
  int row = blockIdx.x, tid = threadIdx.x;
  int lane = tid & 63, wave = tid >> 6;
  const float* xr = x + (size_t)row * 512;
  float a = xr[2 * tid], b = xr[2 * tid + 1];
  __shared__ float red[8];
  float s = wredsum(a + b);
  if (lane == 0) red[wave] = s;
  __syncthreads();
  float mean = (red[0] + red[1] + red[2] + red[3]) * (1.0f / 512.0f);
  float da = a - mean, db = b - mean;
  float vs = wredsum(da * da + db * db);
  if (lane == 0) red[4 + wave] = vs;
  __syncthreads();
  float var = (red[4] + red[5] + red[6] + red[7]) * (1.0f / 512.0f);
  float rstd = rsqrtf(var + 1e-5f);
  int c = 2 * tid;
  u16 o0 = f2b(da * rstd * gamma[c] + beta[c]);
  u16 o1 = f2b(db * rstd * gamma[c + 1] + beta[c + 1]);
  *(u32*)&xn[(size_t)row * 512 + c] = (u32)o0 | ((u32)o1 << 16);
}

// ------------- transpose f32 [R][C] -> bf16 [C][R] (weights) -------------
__global__ __launch_bounds__(256) void transpose_w(const float* __restrict__ in,
                                                   u16* __restrict__ out, int R, int C) {
  __shared__ float t[64][65];
  int c0 = blockIdx.x * 64, r0 = blockIdx.y * 64;
  int tid = threadIdx.x;
  int r = tid >> 2, cs = (tid & 3) * 16;
  const float* src = in + (size_t)(r0 + r) * C + c0 + cs;
#pragma unroll
  for (int e = 0; e < 16; e++) t[r][cs + e] = src[e];
  __syncthreads();
  int c = tid >> 2, rs = (tid & 3) * 16;
  u16* dst = out + (size_t)(c0 + c) * R + r0 + rs;
#pragma unroll
  for (int e = 0; e < 16; e++) dst[e] = f2b(t[rs + e][c]);
}

// ------------- transpose bf16 src[bh][4096][64] -> dst[bh][64][4096] -------------
__global__ __launch_bounds__(256) void transpose_k(const u16* __restrict__ k,
                                                   u16* __restrict__ kT) {
  __shared__ u16 t[64][72];
  int bh = blockIdx.y, i0 = blockIdx.x * 64;
  int tid = threadIdx.x;
  int r = tid >> 2, ds = (tid & 3) * 16;
  const u16* src = k + (((size_t)bh * 4096) + i0 + r) * 64 + ds;
#pragma unroll
  for (int e = 0; e < 16; e++) t[r][ds + e] = src[e];
  __syncthreads();
  int d = tid >> 2, is = (tid & 3) * 16;
  u16* dst = kT + ((size_t)bh * 64 + d) * 4096 + i0 + is;
#pragma unroll
  for (int e = 0; e < 16; e++) dst[e] = t[is + e][d];
}

// ------------- landmark means -> hi/lo planes + optional frag-ordered hi copy -------------
__global__ __launch_bounds__(256) void landmark_mean(const u16* __restrict__ src,
                                                     u16* __restrict__ dh,
                                                     u16* __restrict__ dl,
                                                     u16* __restrict__ dF) {
  int gid = blockIdx.x * 4 + (threadIdx.x >> 6);
  int lane = threadIdx.x & 63;
  int bh = gid >> 8, lm = gid & 255;
  const u16* p = src + (((size_t)bh * 4096) + lm * 16) * 64 + lane;
  float s = 0.f;
#pragma unroll
  for (int t = 0; t < 16; t++) s += b2f(p[t * 64]);
  float m = s * (1.0f / 16.0f);
  u16 hi = f2b(m);
  size_t idx = ((size_t)bh * 256 + lm) * 64 + lane;
  dh[idx] = hi;
  dl[idx] = f2b(m - b2f(hi));
  if (dF) {
    size_t a = ((((size_t)bh * 16 + (lm >> 4)) * 2 + (lane >> 5)) * 512) +
               (((lane >> 3) & 3) * 128) + ((lm & 15) * 8) + (lane & 7);
    dF[a] = hi;
  }
}

// ---------------- big bf16 NT GEMM: C = A[M][K] * Bt[N][K]^T ----------------
// Direct-store epilogue + register prefetch; BK=64 (8 K-steps for K=512).
template <int MODE>
__global__ __launch_bounds__(256) void gemm_bf16_nt(
    const u16* __restrict__ A, const u16* __restrict__ Bt, int K,
    u16* __restrict__ oq, u16* __restrict__ ok, u16* __restrict__ ov,
    const float* __restrict__ xres, const float* __restrict__ bias,
    float* __restrict__ oc) {
  constexpr int BM = 128, BN = 128, BK = 64, LDT = BK + 8;
  __shared__ __align__(16) u16 Al[BM][LDT];
  __shared__ __align__(16) u16 Bl[BN][LDT];
  int tid = threadIdx.x;
  int lane = tid & 63, wave = tid >> 6;
  int bm = blockIdx.x * BM, bn = blockIdx.y * BN;
  int wm = (wave >> 1) * 64, wn = (wave & 1) * 64;
  int l15 = lane & 15, g = lane >> 4;
  // staging: thread covers rows r and r+64, col chunk c16 (16 u16 = 2 x u32x4)
  int r = tid >> 2, c16 = (tid & 3) * 16;
  auto srcA = [&](int rr, int kc, int kt) -> const u16* {
    if (MODE == 0) return A + (size_t)(bm + rr) * K + kt + kc;
    int m = bm + rr, kk = kt + kc;
    return A + ((((size_t)(m >> 12)) * 8 + (kk >> 6)) * 4096 + (m & 4095)) * 64 + (kk & 63);
  };
  u32x4 a00 = *(const u32x4*)srcA(r, c16, 0);
  u32x4 a01 = *(const u32x4*)(srcA(r, c16, 0) + 8);
  u32x4 a10 = *(const u32x4*)srcA(r + 64, c16, 0);
  u32x4 a11 = *(const u32x4*)(srcA(r + 64, c16, 0) + 8);
  const u16* pb0 = Bt + (size_t)(bn + r) * K + c16;
  const u16* pb1 = Bt + (size_t)(bn + r + 64) * K + c16;
  u32x4 b00 = *(const u32x4*)pb0;
  u32x4 b01 = *(const u32x4*)(pb0 + 8);
  u32x4 b10 = *(const u32x4*)pb1;
  u32x4 b11 = *(const u32x4*)(pb1 + 8);
  f32x4 acc[4][4] = {};
  for (int kt = 0; kt < K; kt += BK) {
    __syncthreads();
    *(u32x4*)&Al[r][c16] = a00;
    *(u32x4*)&Al[r][c16 + 8] = a01;
    *(u32x4*)&Al[r + 64][c16] = a10;
    *(u32x4*)&Al[r + 64][c16 + 8] = a11;
    *(u32x4*)&Bl[r][c16] = b00;
    *(u32x4*)&Bl[r][c16 + 8] = b01;
    *(u32x4*)&Bl[r + 64][c16] = b10;
    *(u32x4*)&Bl[r + 64][c16 + 8] = b11;
    __syncthreads();
    if (kt + BK < K) {
      int kn = kt + BK;
      a00 = *(const u32x4*)srcA(r, c16, kn);
      a01 = *(const u32x4*)(srcA(r, c16, kn) + 8);
      a10 = *(const u32x4*)srcA(r + 64, c16, kn);
      a11 = *(const u32x4*)(srcA(r + 64, c16, kn) + 8);
      b00 = *(const u32x4*)(pb0 + kn);
      b01 = *(const u32x4*)(pb0 + kn + 8);
      b10 = *(const u32x4*)(pb1 + kn);
      b11 = *(const u32x4*)(pb1 + kn + 8);
    }
#pragma unroll
    for (int ks = 0; ks < 2; ks++) {
      int ko = ks * 32 + 8 * g;
      bf16x8 af[4], bf_[4];
#pragma unroll
      for (int i = 0; i < 4; i++) af[i] = lds_frag(&Al[wm + i * 16 + l15][ko]);
#pragma unroll
      for (int i = 0; i < 4; i++) bf_[i] = lds_frag(&Bl[wn + i * 16 + l15][ko]);
#pragma unroll
      for (int mi = 0; mi < 4; mi++)
#pragma unroll
        for (int ni = 0; ni < 4; ni++) acc[mi][ni] = mfma16(af[mi], bf_[ni], acc[mi][ni]);
    }
  }
  if (MODE == 0) {
    int tensor = bn / 512;
    float scale = (tensor == 0) ? 0.125f : 1.0f;
    u16* base = (tensor == 0) ? oq : (tensor == 1 ? ok : ov);
#pragma unroll
    for (int mi = 0; mi < 4; mi++)
#pragma unroll
      for (int ni = 0; ni < 4; ni++) {
        int cw = (bn % 512) + wn + ni * 16 + l15;
        int h = cw >> 6, d = cw & 63;
#pragma unroll
        for (int rr = 0; rr < 4; rr++) {
          int m = bm + wm + mi * 16 + 4 * g + rr;
          int b = m >> 12, i = m & 4095;
          base[(((size_t)(b * 8 + h)) * 4096 + i) * 64 + d] = f2b(acc[mi][ni][rr] * scale);
        }
      }
  } else {
#pragma unroll
    for (int mi = 0; mi < 4; mi++)
#pragma unroll
      for (int ni = 0; ni < 4; ni++) {
        int col = bn + wn + ni * 16 + l15;
#pragma unroll
        for (int rr = 0; rr < 4; rr++) {
          int m = bm + wm + mi * 16 + 4 * g + rr;
          oc[(size_t)m * 512 + col] =
              acc[mi][ni][rr] + xres[(size_t)m * 512 + col] + bias[col];
        }
      }
  }
}

// ---------------- NS-chain GEMM, 64x64 tile, BK=64 (4 barriers/dispatch), padded LDS ----------------
// PREC=1: hi/lo inputs (3 MFMA/product). PREC=0: hi-only (1 MFMA/product).
// wlC/wlT: write the lo plane of C / T (skip when consumer is hi-only -> dead traffic).
template <int OMODE, int PREC>
__global__ __launch_bounds__(256) void ns_gemm(
    const u16* __restrict__ Ahg, const u16* __restrict__ Alg,
    const u16* __restrict__ Bhg, const u16* __restrict__ Blg, int K, int sA, int sB,
    u16* __restrict__ Ch, u16* __restrict__ Cl2, u16* __restrict__ Th, u16* __restrict__ Tl,
    float* __restrict__ Cf, u16* __restrict__ Tu,
    float cC, float aC, float cT, float aT, int wrC, int wrT, int wlC, int wlT) {
  __shared__ __align__(16) u16 Ahs[64][72], Als[64][72], Bhs[64][72], Bls[64][72];
  int bz = blockIdx.z;
  int tid = threadIdx.x, lane = tid & 63, wave = tid >> 6;
  int l15 = lane & 15, g = lane >> 4;
  int bm = blockIdx.x * 64, bn = blockIdx.y * 64;
  int wm = (wave >> 1) * 32, wn = (wave & 1) * 32;
  const u16* Ah0 = Ahg + (size_t)bz * sA;
  const u16* Al0 = Alg + (size_t)bz * sA;
  const u16* Bh0 = Bhg + (size_t)bz * sB;
  const u16* Bl0 = Blg + (size_t)bz * sB;
  int r = tid >> 2, c16 = (tid & 3) * 16;
  const u16* pa = Ah0 + (size_t)(bm + r) * K + c16;
  const u16* pal = Al0 + (size_t)(bm + r) * K + c16;
  const u16* pb = Bh0 + (size_t)(bn + r) * K + c16;
  const u16* pbl = Bl0 + (size_t)(bn + r) * K + c16;
  u32x4 ra0 = *(const u32x4*)pa, ra1 = *(const u32x4*)(pa + 8);
  u32x4 rc0 = *(const u32x4*)pb, rc1 = *(const u32x4*)(pb + 8);
  u32x4 rb0, rb1, rd0, rd1;
  if (PREC) {
    rb0 = *(const u32x4*)pal;
    rb1 = *(const u32x4*)(pal + 8);
    rd0 = *(const u32x4*)pbl;
    rd1 = *(const u32x4*)(pbl + 8);
  }
  f32x4 acc[2][2] = {};
  int nt = K >> 6;
  for (int t = 0; t < nt; t++) {
    __syncthreads();
    *(u32x4*)&Ahs[r][c16] = ra0;
    *(u32x4*)&Ahs[r][c16 + 8] = ra1;
    *(u32x4*)&Bhs[r][c16] = rc0;
    *(u32x4*)&Bhs[r][c16 + 8] = rc1;
    if (PREC) {
      *(u32x4*)&Als[r][c16] = rb0;
      *(u32x4*)&Als[r][c16 + 8] = rb1;
      *(u32x4*)&Bls[r][c16] = rd0;
      *(u32x4*)&Bls[r][c16 + 8] = rd1;
    }
    __syncthreads();
    if (t + 1 < nt) {
      int kt = (t + 1) << 6;
      ra0 = *(const u32x4*)(pa + kt);
      ra1 = *(const u32x4*)(pa + kt + 8);
      rc0 = *(const u32x4*)(pb + kt);
      rc1 = *(const u32x4*)(pb + kt + 8);
      if (PREC) {
        rb0 = *(const u32x4*)(pal + kt);
        rb1 = *(const u32x4*)(pal + kt + 8);
        rd0 = *(const u32x4*)(pbl + kt);
        rd1 = *(const u32x4*)(pbl + kt + 8);
      }
    }
#pragma unroll
    for (int ks = 0; ks < 2; ks++) {
      int ko = ks * 32 + 8 * g;
      bf16x8 ah[2], al[2], bh_[2], bl_[2];
#pragma unroll
      for (int i = 0; i < 2; i++) {
        int ro = wm + i * 16 + l15;
        int rn = wn + i * 16 + l15;
        ah[i] = lds_frag(&Ahs[ro][ko]);
        bh_[i] = lds_frag(&Bhs[rn][ko]);
        if (PREC) {
          al[i] = lds_frag(&Als[ro][ko]);
          bl_[i] = lds_frag(&Bls[rn][ko]);
        }
      }
#pragma unroll
      for (int mi = 0; mi < 2; mi++)
#pragma unroll
        for (int ni = 0; ni < 2; ni++) {
          acc[mi][ni] = mfma16(ah[mi], bh_[ni], acc[mi][ni]);
          if (PREC) {
            acc[mi][ni] = mfma16(ah[mi], bl_[ni], acc[mi][ni]);
            acc[mi][ni] = mfma16(al[mi], bh_[ni], acc[mi][ni]);
          }
        }
    }
  }
#pragma unroll
  for (int mi = 0; mi < 2; mi++)
#pragma unroll
    for (int ni = 0; ni < 2; ni++) {
      int r0 = bm + wm + mi * 16 + 4 * g;
      int cg = bn + wn + ni * 16 + l15;
      f32x4 a = acc[mi][ni];
      if (OMODE == 1) {
        float* c = Cf + (size_t)bz * 65536;
#pragma unroll
        for (int rr = 0; rr < 4; rr++)
          c[(size_t)(r0 + rr) * 256 + cg] = aC * a[rr] + ((r0 + rr) == cg ? cC : 0.f);
      } else if (OMODE == 2) {
        u16 pp[4];
#pragma unroll
        for (int rr = 0; rr < 4; rr++) pp[rr] = f2b(aT * a[rr]);
        u16* tp = Tu + ((((size_t)bz * 4 + (cg >> 4)) * 8 + (r0 >> 5)) * 512) +
                  (((r0 >> 3) & 3) * 128) + ((cg & 15) * 8) + (r0 & 7);
        *(u32*)tp = (u32)pp[0] | ((u32)pp[1] << 16);
        *(u32*)(tp + 2) = (u32)pp[2] | ((u32)pp[3] << 16);
      } else {
        if (wrC) {
#pragma unroll
          for (int rr = 0; rr < 4; rr++) {
            float v = aC * a[rr] + ((r0 + rr) == cg ? cC : 0.f);
            u16 hi = f2b(v);
            size_t idx = (size_t)bz * 65536 + (size_t)(r0 + rr) * 256 + cg;
            Ch[idx] = hi;
            if (wlC) Cl2[idx] = f2b(v - b2f(hi));
          }
        }
        if (wrT) {
          u16 ph[4], pl[4];
#pragma unroll
          for (int rr = 0; rr < 4; rr++) {
            float v = aT * a[rr] + ((r0 + rr) == cg ? cT : 0.f);
            ph[rr] = f2b(v);
            if (wlT) pl[rr] = f2b(v - b2f(ph[rr]));
          }
          size_t idx = (size_t)bz * 65536 + (size_t)cg * 256 + r0;
          *(u32*)&Th[idx] = (u32)ph[0] | ((u32)ph[1] << 16);
          *(u32*)&Th[idx + 2] = (u32)ph[2] | ((u32)ph[3] << 16);
          if (wlT) {
            *(u32*)&Tl[idx] = (u32)pl[0] | ((u32)pl[1] << 16);
            *(u32*)&Tl[idx + 2] = (u32)pl[2] | ((u32)pl[3] << 16);
          }
        }
      }
    }
}

// ---------------- row softmax over 256 (in place) + hi/lo plane output ----------------
__global__ __launch_bounds__(256) void softmax256(float* __restrict__ S,
                                                  u16* __restrict__ Sh,
                                                  u16* __restrict__ Sl) {
  int row = blockIdx.x * 4 + (threadIdx.x >> 6);
  int lane = threadIdx.x & 63;
  float* r = S + (size_t)row * 256;
  f32x4 vv = *(f32x4*)&r[lane * 4];
  float mx = wredmax(fmaxf(fmaxf(vv[0], vv[1]), fmaxf(vv[2], vv[3])));
  vv[0] = __expf(vv[0] - mx);
  vv[1] = __expf(vv[1] - mx);
  vv[2] = __expf(vv[2] - mx);
  vv[3] = __expf(vv[3] - mx);
  float sm = wredsum(vv[0] + vv[1] + vv[2] + vv[3]);
  vv *= (1.0f / sm);
  *(f32x4*)&r[lane * 4] = vv;
  u16 h[4], l[4];
#pragma unroll
  for (int e = 0; e < 4; e++) {
    h[e] = f2b(vv[e]);
    l[e] = f2b(vv[e] - b2f(h[e]));
  }
  size_t p = (size_t)row * 256 + lane * 4;
  *(u32*)&Sh[p] = (u32)h[0] | ((u32)h[1] << 16);
  *(u32*)&Sh[p + 2] = (u32)h[2] | ((u32)h[3] << 16);
  *(u32*)&Sl[p] = (u32)l[0] | ((u32)l[1] << 16);
  *(u32*)&Sl[p + 2] = (u32)l[2] | ((u32)l[3] << 16);
}

// ---------------- pinv scale, stage 1 ----------------
__global__ __launch_bounds__(256) void pinv_part(const float* __restrict__ mat,
                                                 float* __restrict__ colpart,
                                                 float* __restrict__ scal) {
  int blk = blockIdx.x;
  int bh = blk >> 3, ch = blk & 7;
  const float* m = mat + (size_t)bh * 65536 + (size_t)ch * 32 * 256;
  int tid = threadIdx.x, lane = tid & 63, wv = tid >> 6;
  float cp = 0.f;
#pragma unroll 4
  for (int r2 = 0; r2 < 32; r2++) cp += m[r2 * 256 + tid];
  colpart[(size_t)blk * 256 + tid] = cp;
  float rmax = 0.f;
#pragma unroll
  for (int rr = 0; rr < 8; rr++) {
    f32x4 v = *(const f32x4*)&m[(wv * 8 + rr) * 256 + lane * 4];
    float s = wredsum(v[0] + v[1] + v[2] + v[3]);
    rmax = fmaxf(rmax, s);
  }
  if (lane == 0) atomicMax((int*)&scal[1], __float_as_int(rmax));
}

// ---------------- pinv scale, stage 2 ----------------
__global__ __launch_bounds__(256) void pinv_fin(const float* __restrict__ colpart,
                                                float* __restrict__ scal) {
  int tid = threadIdx.x;
  float mx = 0.f;
  for (int bh = 0; bh < 32; bh++) {
    float s = 0.f;
#pragma unroll
    for (int ch = 0; ch < 8; ch++) s += colpart[((size_t)bh * 8 + ch) * 256 + tid];
    mx = fmaxf(mx, s);
  }
  mx = wredmax(mx);
  __shared__ float red[4];
  if ((tid & 63) == 0) red[tid >> 6] = mx;
  __syncthreads();
  if (tid == 0) {
    float a = fmaxf(fmaxf(red[0], red[1]), fmaxf(red[2], red[3]));
    atomicMax((int*)&scal[0], __float_as_int(a));
  }
}

// ---------------- pinv init: z = matT*s, zT = mat*s  (hi/lo planes) ----------------
__global__ __launch_bounds__(256) void pinv_init(const float* __restrict__ mat,
                                                 const float* __restrict__ scal,
                                                 u16* __restrict__ zh, u16* __restrict__ zl,
                                                 u16* __restrict__ zth, u16* __restrict__ ztl) {
  size_t idx = (size_t)blockIdx.x * 256 + threadIdx.x;
  int bh = (int)(idx >> 16);
  int i = (int)((idx >> 8) & 255), j = (int)(idx & 255);
  float s = 1.0f / (scal[0] * scal[1]);
  float val = mat[idx] * s;
  u16 hi = f2b(val);
  u16 lo = f2b(val - b2f(hi));
  zth[idx] = hi;
  ztl[idx] = lo;
  size_t tixd = ((size_t)bh << 16) + ((size_t)j << 8) + i;
  zh[tixd] = hi;
  zl[tixd] = lo;
}

// ------- attn3 split-KV flash v3: merged ss chains (2x ILP, one LDS round-trip/tile) -------
__global__ __launch_bounds__(512) void attn3_split(const u16* __restrict__ qlh,
                                                   const u16* __restrict__ k,
                                                   const u16* __restrict__ vT,
                                                   float* __restrict__ pacc,
                                                   float* __restrict__ ml) {
  __shared__ __align__(16) u16 kb[64][72];
  __shared__ __align__(16) u16 vtb[64][72];
  __shared__ __align__(16) u16 Pb[8][32][72];
  int tid = threadIdx.x, lane = tid & 63, wv = tid >> 6;
  int l15 = lane & 15, g = lane >> 4;
  int bh = blockIdx.y, kvc = blockIdx.x;
  const u16* kb_g = k + ((size_t)bh * 4096 + (size_t)kvc * 512) * 64;
  const u16* vb_g = vT + (size_t)bh * 64 * 4096 + (size_t)kvc * 512;
  bf16x8 aq[2][2];
#pragma unroll
  for (int ss = 0; ss < 2; ss++) {
    const u16* qlp = qlh + ((size_t)bh * 256 + wv * 32 + ss * 16 + l15) * 64 + 8 * g;
    aq[ss][0] = g_frag(qlp);
    aq[ss][1] = g_frag(qlp + 32);
  }
  int sr = tid >> 3, sc = (tid & 7) * 8;
  u32x4 rk = *(const u32x4*)(kb_g + (size_t)sr * 64 + sc);
  u32x4 rv = *(const u32x4*)(vb_g + (size_t)sr * 4096 + sc);
  f32x4 minit = {-1e30f, -1e30f, -1e30f, -1e30f};
  f32x4 mreg[2] = {minit, minit};
  f32x4 lreg[2] = {};
  f32x4 oacc[2][4] = {};
  for (int t = 0; t < 8; t++) {
    __syncthreads();
    *(u32x4*)&kb[sr][sc] = rk;
    *(u32x4*)&vtb[sr][sc] = rv;
    __syncthreads();
    if (t < 7) {
      rk = *(const u32x4*)(kb_g + (size_t)(t + 1) * 4096 + (size_t)sr * 64 + sc);
      rv = *(const u32x4*)(vb_g + (size_t)(t + 1) * 64 + (size_t)sr * 4096 + sc);
    }
    // QK^T for both ss halves; kb fragments read once and shared
    f32x4 sa[2][4] = {};
#pragma unroll
    for (int nf = 0; nf < 4; nf++) {
      bf16x8 b0 = lds_frag(&kb[nf * 16 + l15][8 * g]);
      bf16x8 b1 = lds_frag(&kb[nf * 16 + l15][8 * g + 32]);
#pragma unroll
      for (int ss = 0; ss < 2; ss++) {
        sa[ss][nf] = mfma16(aq[ss][0], b0, sa[ss][nf]);
        sa[ss][nf] = mfma16(aq[ss][1], b1, sa[ss][nf]);
      }
    }
    // online softmax for both ss (independent chains -> 2x VALU ILP)
#pragma unroll
    for (int ss = 0; ss < 2; ss++) {
      f32x4 mn, corr;
#pragma unroll
      for (int r = 0; r < 4; r++) {
        float m_ = fmaxf(fmaxf(sa[ss][0][r], sa[ss][1][r]),
                         fmaxf(sa[ss][2][r], sa[ss][3][r]));
#pragma unroll
        for (int msk = 1; msk < 16; msk <<= 1) m_ = fmaxf(m_, __shfl_xor(m_, msk));
        mn[r] = fmaxf(mreg[ss][r], m_);
        corr[r] = __expf(mreg[ss][r] - mn[r]);
        mreg[ss][r] = mn[r];
      }
      f32x4 ps = {};
#pragma unroll
      for (int nf = 0; nf < 4; nf++)
#pragma unroll
        for (int r = 0; r < 4; r++) {
          sa[ss][nf][r] = __expf(sa[ss][nf][r] - mn[r]);
          ps[r] += sa[ss][nf][r];
        }
#pragma unroll
      for (int r = 0; r < 4; r++) {
#pragma unroll
        for (int msk = 1; msk < 16; msk <<= 1) ps[r] += __shfl_xor(ps[r], msk);
        lreg[ss][r] = lreg[ss][r] * corr[r] + ps[r];
      }
#pragma unroll
      for (int nf = 0; nf < 4; nf++) oacc[ss][nf] *= corr;
#pragma unroll
      for (int nf = 0; nf < 4; nf++)
#pragma unroll
        for (int r = 0; r < 4; r++)
          Pb[wv][ss * 16 + 4 * g + r][nf * 16 + l15] = f2b(sa[ss][nf][r]);
    }
    asm volatile("s_waitcnt lgkmcnt(0)" ::: "memory");
    __builtin_amdgcn_sched_barrier(0);
    bf16x8 ap[2][2];
#pragma unroll
    for (int ss = 0; ss < 2; ss++) {
      ap[ss][0] = lds_frag(&Pb[wv][ss * 16 + l15][8 * g]);
      ap[ss][1] = lds_frag(&Pb[wv][ss * 16 + l15][8 * g + 32]);
    }
    // PV for both ss; vtb fragments read once and shared
#pragma unroll
    for (int nf = 0; nf < 4; nf++) {
      bf16x8 b0 = lds_frag(&vtb[nf * 16 + l15][8 * g]);
      bf16x8 b1 = lds_frag(&vtb[nf * 16 + l15][8 * g + 32]);
#pragma unroll
      for (int ss = 0; ss < 2; ss++) {
        oacc[ss][nf] = mfma16(ap[ss][0], b0, oacc[ss][nf]);
        oacc[ss][nf] = mfma16(ap[ss][1], b1, oacc[ss][nf]);
      }
    }
  }
  size_t pb = (size_t)(bh * 8 + kvc) * 64;
#pragma unroll
  for (int ss = 0; ss < 2; ss++) {
    int qbase = wv * 32 + ss * 16;
#pragma unroll
    for (int nf = 0; nf < 4; nf++)
      *(f32x4*)&pacc[(pb + nf * 16 + l15) * 256 + qbase + 4 * g] = oacc[ss][nf];
    if (l15 == 0) {
#pragma unroll
      for (int r = 0; r < 4; r++) {
        size_t mi = ((size_t)(bh * 8 + kvc) * 256 + qbase + 4 * g + r) * 2;
        ml[mi] = mreg[ss][r];
        ml[mi + 1] = lreg[ss][r];
      }
    }
  }
}

// ------- attn3 combine: merge 8 kv-chunk partials -> w3 hi/lo planes -------
__global__ __launch_bounds__(256) void attn3_fin(const float* __restrict__ pacc,
                                                 const float* __restrict__ ml,
                                                 u16* __restrict__ w3h,
                                                 u16* __restrict__ w3l) {
  int dc = blockIdx.x, bh = blockIdx.y;
  int i = threadIdx.x;
  float m[8], l[8], w[8];
  float M = -1e30f;
#pragma unroll
  for (int kv = 0; kv < 8; kv++) {
    size_t mi = ((size_t)(bh * 8 + kv) * 256 + i) * 2;
    m[kv] = ml[mi];
    l[kv] = ml[mi + 1];
    M = fmaxf(M, m[kv]);
  }
  float den = 0.f;
#pragma unroll
  for (int kv = 0; kv < 8; kv++) {
    w[kv] = __expf(m[kv] - M);
    den += w[kv] * l[kv];
  }
  float inv = 1.0f / den;
#pragma unroll
  for (int dd = 0; dd < 16; dd++) {
    int d = dc * 16 + dd;
    float num = 0.f;
#pragma unroll
    for (int kv = 0; kv < 8; kv++)
      num += w[kv] * pacc[((size_t)(bh * 8 + kv) * 64 + d) * 256 + i];
    float val = num * inv;
    u16 hi = f2b(val);
    size_t o = ((size_t)bh * 64 + d) * 256 + i;
    w3h[o] = hi;
    w3l[o] = f2b(val - b2f(hi));
  }
}

// ------- attn1 (MFMA, barrier-free): conv phase hoisted before softmax -------
__global__ __launch_bounds__(256, 4) void attn1_mfma(const u16* __restrict__ q,
                                                     const u16* __restrict__ kF,
                                                     const u16* __restrict__ zwF,
                                                     const u16* __restrict__ vT,
                                                     const float* __restrict__ rker,
                                                     u16* __restrict__ out_h) {
  __shared__ __align__(16) u16 Pl[64][258];
  int tid = threadIdx.x, lane = tid & 63, wv = tid >> 6;
  int l15 = lane & 15, g = lane >> 4;
  int bh = blockIdx.y, h = bh & 7;
  int i0 = blockIdx.x * 64;
  const u16* qp = q + ((size_t)bh * 4096 + i0 + wv * 16 + l15) * 64 + 8 * g;
  bf16x8 aq0 = __builtin_bit_cast(bf16x8, *(const u32x4*)qp);
  bf16x8 aq1 = __builtin_bit_cast(bf16x8, *(const u32x4*)(qp + 32));
  u16 kb16 = (lane < 33) ? f2b(rker[h * 33 + lane]) : (u16)0;
  const u16* kfb = kF + (size_t)bh * 16384 + (size_t)lane * 8;
  f32x4 sacc[16] = {};
#pragma unroll
  for (int nf = 0; nf < 16; nf++) {
    bf16x8 b0 = g_frag(kfb + (nf * 2 + 0) * 512);
    bf16x8 b1 = g_frag(kfb + (nf * 2 + 1) * 512);
    sacc[nf] = mfma16(aq0, b0, sacc[nf]);
    sacc[nf] = mfma16(aq1, b1, sacc[nf]);
  }
  bf16x8 band[2];
#pragma unroll
  for (int ks = 0; ks < 2; ks++) {
    u16 bb[8];
#pragma unroll
    for (int j = 0; j < 8; j++) {
      int idx = 32 * ks + 8 * g + j - l15;
      u16 vsh = (u16)__shfl((int)kb16, idx & 63);
      bb[j] = (idx >= 0 && idx <= 32) ? vsh : (u16)0;
    }
    band[ks] = __builtin_bit_cast(bf16x8, *(u32x4*)bb);
  }
  f32x4 cacc[4] = {};
#pragma unroll
  for (int nf = 0; nf < 4; nf++) {
    int d = nf * 16 + l15;
    const u16* vp = vT + ((size_t)bh * 64 + d) * 4096;
#pragma unroll
    for (int ks = 0; ks < 2; ks++) {
      int col0 = i0 - 16 + 16 * wv + 32 * ks + 8 * g;
      bf16x8 vf;
      if (col0 >= 0 && col0 + 7 < 4096) {
        vf = g_frag(vp + col0);
      } else {
        u16 tmp[8];
#pragma unroll
        for (int j = 0; j < 8; j++) {
          int c = col0 + j;
          tmp[j] = (c >= 0 && c < 4096) ? vp[c] : (u16)0;
        }
        vf = __builtin_bit_cast(bf16x8, *(u32x4*)tmp);
      }
      cacc[nf] = mfma16(band[ks], vf, cacc[nf]);
    }
  }
  f32x4 mx;
#pragma unroll
  for (int r = 0; r < 4; r++) {
    float m_ = sacc[0][r];
#pragma unroll
    for (int nf = 1; nf < 16; nf++) m_ = fmaxf(m_, sacc[nf][r]);
#pragma unroll
    for (int msk = 1; msk < 16; msk <<= 1) m_ = fmaxf(m_, __shfl_xor(m_, msk));
    mx[r] = m_;
  }
  f32x4 ls = {};
#pragma unroll
  for (int nf = 0; nf < 16; nf++)
#pragma unroll
    for (int r = 0; r < 4; r++) {
      sacc[nf][r] = __expf(sacc[nf][r] - mx[r]);
      ls[r] += sacc[nf][r];
    }
  f32x4 invl;
#pragma unroll
  for (int r = 0; r < 4; r++) {
#pragma unroll
    for (int msk = 1; msk < 16; msk <<= 1) ls[r] += __shfl_xor(ls[r], msk);
    invl[r] = 1.0f / ls[r];
  }
#pragma unroll
  for (int nf = 0; nf < 16; nf++)
#pragma unroll
    for (int r = 0; r < 4; r++) Pl[wv * 16 + 4 * g + r][nf * 16 + l15] = f2b(sacc[nf][r]);
  asm volatile("s_waitcnt lgkmcnt(0)" ::: "memory");
  __builtin_amdgcn_sched_barrier(0);
  bf16x8 ap[8];
#pragma unroll
  for (int ks = 0; ks < 8; ks++) ap[ks] = lds_frag(&Pl[wv * 16 + l15][8 * g + 32 * ks]);
  const u16* zfb = zwF + (size_t)bh * 16384 + (size_t)lane * 8;
  f32x4 oacc[4] = {};
#pragma unroll
  for (int nf = 0; nf < 4; nf++) {
#pragma unroll
    for (int ks = 0; ks < 8; ks++) {
      bf16x8 b = g_frag(zfb + (nf * 8 + ks) * 512);
      oacc[nf] = mfma16(ap[ks], b, oacc[nf]);
    }
  }
#pragma unroll
  for (int nf = 0; nf < 4; nf++) {
    int colc = nf * 16 + l15;
#pragma unroll
    for (int r = 0; r < 4; r++) {
      float val = oacc[nf][r] * invl[r] + cacc[nf][r];
      out_h[((size_t)bh * 4096 + i0 + wv * 16 + 4 * g + r) * 64 + colc] = f2b(val);
    }
  }
}

extern "C" void kernel_launch(void* const* d_in, const int* in_sizes, int n_in,
                              void* d_out, int out_size, void* d_ws, size_t ws_size,
                              hipStream_t stream) {
  (void)in_sizes; (void)n_in; (void)out_size;
  const float* x = (const float*)d_in[0];
  const float* w_qkv = (const float*)d_in[1];
  const float* w_out = (const float*)d_in[2];
  const float* b_out = (const float*)d_in[3];
  const float* res_k = (const float*)d_in[4];
  const float* gamma = (const float*)d_in[5];
  const float* beta = (const float*)d_in[6];
  float* out = (float*)d_out;

  char* p = (char*)d_ws;
  auto alloc = [&](size_t bytes) {
    char* r = p;
    p += (bytes + 255) & ~(size_t)255;
    return r;
  };
  const size_t BH = 32;
  const size_t PLANE = BH * 65536 * 2;  // 4.19MB u16 plane [32][256][256]
  const size_t SMALL = BH * 256 * 64 * 2;
  u16* xn = (u16*)alloc(BH * 4096 * 64 * 2);  // aliased: vT after qkv
  u16* vT = xn;
  u16* wTq = (u16*)alloc(1536 * 512 * 2);
  u16* wTo = (u16*)alloc(512 * 512 * 2);
  u16* q = (u16*)alloc(BH * 4096 * 64 * 2);
  u16* k = (u16*)alloc(BH * 4096 * 64 * 2);
  u16* v = (u16*)alloc(BH * 4096 * 64 * 2);
  u16* qlh = (u16*)alloc(SMALL);
  u16* qll = (u16*)alloc(SMALL);
  u16* klh = (u16*)alloc(SMALL);
  u16* kll = (u16*)alloc(SMALL);
  u16* kF = (u16*)alloc(SMALL);
  float* mat = (float*)alloc(BH * 65536 * 4);  // aliased: t4 planes after pinv_init
  u16* t4h = (u16*)mat;
  u16* t4l = t4h + BH * 65536;
  u16* math_ = (u16*)alloc(PLANE);
  u16* matl = (u16*)alloc(PLANE);
  u16* zh = (u16*)alloc(PLANE);
  u16* zl = (u16*)alloc(PLANE);
  u16* zth = (u16*)alloc(PLANE);
  u16* ztl = (u16*)alloc(PLANE);
  char* slotB = alloc(4 * PLANE);  // mz hi/lo + s2 hi/lo; aliased: out_h
  u16* mzh = (u16*)slotB;
  u16* mzl = mzh + BH * 65536;
  u16* s2h = mzl + BH * 65536;
  u16* s2l = s2h + BH * 65536;
  u16* out_h = (u16*)slotB;
  u16* t3h = (u16*)alloc(PLANE);
  u16* t3l = (u16*)alloc(PLANE);
  u16* znh = (u16*)alloc(PLANE);
  u16* znl = (u16*)alloc(PLANE);
  u16* znth = (u16*)alloc(PLANE);
  u16* zntl = (u16*)alloc(PLANE);
  u16* w3h = (u16*)alloc(BH * 64 * 256 * 2);
  u16* w3l = (u16*)alloc(BH * 64 * 256 * 2);
  u16* zwF = (u16*)alloc(BH * 64 * 256 * 2);
  float* colpart = (float*)alloc(256 * 256 * 4);
  float* scal = (float*)alloc(256);
  if ((size_t)(p - (char*)d_ws) > ws_size) return;  // insufficient workspace
  // attn3 partials alias dead NS temporaries
  float* pacc = (float*)t3h;   // [32][8][64][256] f32
  float* mlbuf = (float*)znth; // [32][8][256][2] f32

  hipMemsetAsync(scal, 0, 8, stream);
  ln_k<<<16384, 256, 0, stream>>>(x, gamma, beta, xn);
  transpose_w<<<dim3(24, 8), 256, 0, stream>>>(w_qkv, wTq, 512, 1536);
  transpose_w<<<dim3(8, 8), 256, 0, stream>>>(w_out, wTo, 512, 512);
  gemm_bf16_nt<0><<<dim3(128, 12), 256, 0, stream>>>(xn, wTq, 512, q, k, v, nullptr,
                                                     nullptr, nullptr);
  landmark_mean<<<2048, 256, 0, stream>>>(q, qlh, qll, nullptr);
  landmark_mean<<<2048, 256, 0, stream>>>(k, klh, kll, kF);
  transpose_k<<<dim3(64, 32), 256, 0, stream>>>(v, vT);  // vT aliases xn (xn dead)
  // attn2 logits: mat = q_l @ k_l^T   (K=64, f32 out, hi/lo)
  ns_gemm<1, 1><<<dim3(4, 4, 32), 256, 0, stream>>>(
      qlh, qll, klh, kll, 64, 16384, 16384,
      nullptr, nullptr, nullptr, nullptr, mat, nullptr, 0.f, 1.f, 0.f, 0.f, 0, 0, 0, 0);
  softmax256<<<2048, 256, 0, stream>>>(mat, math_, matl);
  pinv_part<<<256, 256, 0, stream>>>(mat, colpart, scal);
  pinv_fin<<<1, 256, 0, stream>>>(colpart, scal);
  pinv_init<<<8192, 256, 0, stream>>>(mat, scal, zh, zl, zth, ztl);
  u16 *zch = zh, *zcl = zl, *zcth = zth, *zctl = ztl;
  u16 *znh_ = znh, *znl_ = znl, *znth_ = znth, *zntl_ = zntl;
  for (int it = 0; it < 6; it++) {
    dim3 g44(4, 4, 32);
    if (it < 5) {
      // bf16 (hi-only) iterations: lo-plane writes are dead except it=4's d4
      // (whose zn/znt lo feed the hi/lo final iteration).
      int wl4 = (it == 4) ? 1 : 0;
      ns_gemm<0, 0><<<g44, 256, 0, stream>>>(
          math_, matl, zcth, zctl, 256, 65536, 65536,
          mzh, mzl, s2h, s2l, nullptr, nullptr, 0.f, 1.f, 7.f, -1.f, 1, 1, 0, 0);
      ns_gemm<0, 0><<<g44, 256, 0, stream>>>(
          mzh, mzl, s2h, s2l, 256, 65536, 65536,
          nullptr, nullptr, t3h, t3l, nullptr, nullptr, 0.f, 0.f, 15.f, -1.f, 0, 1, 0, 0);
      ns_gemm<0, 0><<<g44, 256, 0, stream>>>(
          mzh, mzl, t3h, t3l, 256, 65536, 65536,
          nullptr, nullptr, t4h, t4l, nullptr, nullptr, 0.f, 0.f, 13.f, -1.f, 0, 1, 0, 0);
      ns_gemm<0, 0><<<g44, 256, 0, stream>>>(
          zch, zcl, t4h, t4l, 256, 65536, 65536,
          znh_, znl_, znth_, zntl_, nullptr, nullptr, 0.f, 0.25f, 0.f, 0.25f, 1, 1,
          wl4, wl4);
    } else {
      // final iteration in hi/lo
      ns_gemm<0, 1><<<g44, 256, 0, stream>>>(
          math_, matl, zcth, zctl, 256, 65536, 65536,
          mzh, mzl, s2h, s2l, nullptr, nullptr, 0.f, 1.f, 7.f, -1.f, 1, 1, 1, 1);
      ns_gemm<0, 1><<<g44, 256, 0, stream>>>(
          mzh, mzl, s2h, s2l, 256, 65536, 65536,
          nullptr, nullptr, t3h, t3l, nullptr, nullptr, 0.f, 0.f, 15.f, -1.f, 0, 1, 1, 1);
      ns_gemm<0, 1><<<g44, 256, 0, stream>>>(
          mzh, mzl, t3h, t3l, 256, 65536, 65536,
          nullptr, nullptr, t4h, t4l, nullptr, nullptr, 0.f, 0.f, 13.f, -1.f, 0, 1, 1, 1);
      ns_gemm<0, 1><<<g44, 256, 0, stream>>>(
          zch, zcl, t4h, t4l, 256, 65536, 65536,
          znh_, znl_, znth_, zntl_, nullptr, nullptr, 0.f, 0.25f, 0.f, 0.25f, 1, 1, 1, 1);
    }
    u16* t;
    t = zch; zch = znh_; znh_ = t;
    t = zcl; zcl = znl_; znl_ = t;
    t = zcth; zcth = znth_; znth_ = t;
    t = zctl; zctl = zntl_; zntl_ = t;
  }
  attn3_split<<<dim3(8, 32), 512, 0, stream>>>(qlh, k, vT, pacc, mlbuf);
  attn3_fin<<<dim3(4, 32), 256, 0, stream>>>(pacc, mlbuf, w3h, w3l);
  // zwF = frag-ordered (z @ w3)^T  bf16 (hi/lo)
  ns_gemm<2, 1><<<dim3(4, 1, 32), 256, 0, stream>>>(
      zch, zcl, w3h, w3l, 256, 65536, 16384,
      nullptr, nullptr, nullptr, nullptr, nullptr, zwF, 0.f, 0.f, 0.f, 1.f, 0, 0, 0, 0);
  attn1_mfma<<<dim3(64, 32), 256, 0, stream>>>(q, kF, zwF, vT, res_k, out_h);
  gemm_bf16_nt<1><<<dim3(128, 4), 256, 0, stream>>>(out_h, wTo, 512, nullptr, nullptr,
                                                    nullptr, x, b_out, out);
}

// Round 26
// 423.126 us; speedup vs baseline: 1.1209x; 1.0324x over previous
//
#include <hip/hip_runtime.h>
#include <stdint.h>

#define DEV __device__ __forceinline__

typedef unsigned short u16;
typedef unsigned int u32;
using f32x4 = __attribute__((ext_vector_type(4))) float;
using u32x4 = __attribute__((ext_vector_type(4))) u32;
using bf16x8 = __attribute__((ext_vector_type(8))) __bf16;

DEV float b2f(u16 u) { u32 x = ((u32)u) << 16; return __builtin_bit_cast(float, x); }
DEV u16 f2b(float f) {
  u32 x = __builtin_bit_cast(u32, f);
  return (u16)((x + 0x7FFFu + ((x >> 16) & 1u)) >> 16);
}
DEV u32 pk2(float a, float b) { return (u32)f2b(a) | ((u32)f2b(b) << 16); }
DEV bf16x8 lds_frag(const u16* p) { return __builtin_bit_cast(bf16x8, *(const u32x4*)p); }
DEV bf16x8 g_frag(const u16* p) { return __builtin_bit_cast(bf16x8, *(const u32x4*)p); }
DEV f32x4 mfma16(bf16x8 a, bf16x8 b, f32x4 c) {
  return __builtin_amdgcn_mfma_f32_16x16x32_bf16(a, b, c, 0, 0, 0);
}
DEV float wredmax(float v) {
#pragma unroll
  for (int m = 32; m > 0; m >>= 1) v = fmaxf(v, __shfl_xor(v, m));
  return v;
}
DEV float wredsum(float v) {
#pragma unroll
  for (int m = 32; m > 0; m >>= 1) v += __shfl_xor(v, m);
  return v;
}

// ---------------- LayerNorm: x[16384][512] f32 -> xn bf16 ----------------
__global__ __launch_bounds__(256) void ln_k(const float* __restrict__ x,
                                            const float* __restrict__ gamma,
                                            const float* __restrict__ beta,
                                            u16* __restrict__ xn) {
  int row = blockIdx.x, tid = threadIdx.x;
  int lane = tid & 63, wave = tid >> 6;
  const float* xr = x + (size_t)row * 512;
  float a = xr[2 * tid], b = xr[2 * tid + 1];
  __shared__ float red[8];
  float s = wredsum(a + b);
  if (lane == 0) red[wave] = s;
  __syncthreads();
  float mean = (red[0] + red[1] + red[2] + red[3]) * (1.0f / 512.0f);
  float da = a - mean, db = b - mean;
  float vs = wredsum(da * da + db * db);
  if (lane == 0) red[4 + wave] = vs;
  __syncthreads();
  float var = (red[4] + red[5] + red[6] + red[7]) * (1.0f / 512.0f);
  float rstd = rsqrtf(var + 1e-5f);
  int c = 2 * tid;
  u16 o0 = f2b(da * rstd * gamma[c] + beta[c]);
  u16 o1 = f2b(db * rstd * gamma[c + 1] + beta[c + 1]);
  *(u32*)&xn[(size_t)row * 512 + c] = (u32)o0 | ((u32)o1 << 16);
}

// ------------- transpose f32 [R][C] -> bf16 [C][R] (weights) -------------
__global__ __launch_bounds__(256) void transpose_w(const float* __restrict__ in,
                                                   u16* __restrict__ out, int R, int C) {
  __shared__ float t[64][65];
  int c0 = blockIdx.x * 64, r0 = blockIdx.y * 64;
  int tid = threadIdx.x;
  int r = tid >> 2, cs = (tid & 3) * 16;
  const float* src = in + (size_t)(r0 + r) * C + c0 + cs;
#pragma unroll
  for (int e = 0; e < 16; e++) t[r][cs + e] = src[e];
  __syncthreads();
  int c = tid >> 2, rs = (tid & 3) * 16;
  u16* dst = out + (size_t)(c0 + c) * R + r0 + rs;
#pragma unroll
  for (int e = 0; e < 16; e++) dst[e] = f2b(t[rs + e][c]);
}

// ------------- transpose bf16 src[bh][4096][64] -> dst[bh][64][4096] -------------
__global__ __launch_bounds__(256) void transpose_k(const u16* __restrict__ k,
                                                   u16* __restrict__ kT) {
  __shared__ u16 t[64][72];
  int bh = blockIdx.y, i0 = blockIdx.x * 64;
  int tid = threadIdx.x;
  int r = tid >> 2, ds = (tid & 3) * 16;
  const u16* src = k + (((size_t)bh * 4096) + i0 + r) * 64 + ds;
#pragma unroll
  for (int e = 0; e < 16; e++) t[r][ds + e] = src[e];
  __syncthreads();
  int d = tid >> 2, is = (tid & 3) * 16;
  u16* dst = kT + ((size_t)bh * 64 + d) * 4096 + i0 + is;
#pragma unroll
  for (int e = 0; e < 16; e++) dst[e] = t[is + e][d];
}

// ------------- landmark means -> hi/lo planes + optional frag-ordered hi copy -------------
__global__ __launch_bounds__(256) void landmark_mean(const u16* __restrict__ src,
                                                     u16* __restrict__ dh,
                                                     u16* __restrict__ dl,
                                                     u16* __restrict__ dF) {
  int gid = blockIdx.x * 4 + (threadIdx.x >> 6);
  int lane = threadIdx.x & 63;
  int bh = gid >> 8, lm = gid & 255;
  const u16* p = src + (((size_t)bh * 4096) + lm * 16) * 64 + lane;
  float s = 0.f;
#pragma unroll
  for (int t = 0; t < 16; t++) s += b2f(p[t * 64]);
  float m = s * (1.0f / 16.0f);
  u16 hi = f2b(m);
  size_t idx = ((size_t)bh * 256 + lm) * 64 + lane;
  dh[idx] = hi;
  dl[idx] = f2b(m - b2f(hi));
  if (dF) {
    size_t a = ((((size_t)bh * 16 + (lm >> 4)) * 2 + (lane >> 5)) * 512) +
               (((lane >> 3) & 3) * 128) + ((lm & 15) * 8) + (lane & 7);
    dF[a] = hi;
  }
}

// ---------------- big bf16 NT GEMM: C = A[M][K] * Bt[N][K]^T ----------------
// Direct-store epilogue + register prefetch; BK=64 (8 K-steps for K=512).
template <int MODE>
__global__ __launch_bounds__(256) void gemm_bf16_nt(
    const u16* __restrict__ A, const u16* __restrict__ Bt, int K,
    u16* __restrict__ oq, u16* __restrict__ ok, u16* __restrict__ ov,
    const float* __restrict__ xres, const float* __restrict__ bias,
    float* __restrict__ oc) {
  constexpr int BM = 128, BN = 128, BK = 64, LDT = BK + 8;
  __shared__ __align__(16) u16 Al[BM][LDT];
  __shared__ __align__(16) u16 Bl[BN][LDT];
  int tid = threadIdx.x;
  int lane = tid & 63, wave = tid >> 6;
  int bm = blockIdx.x * BM, bn = blockIdx.y * BN;
  int wm = (wave >> 1) * 64, wn = (wave & 1) * 64;
  int l15 = lane & 15, g = lane >> 4;
  // staging: thread covers rows r and r+64, col chunk c16 (16 u16 = 2 x u32x4)
  int r = tid >> 2, c16 = (tid & 3) * 16;
  auto srcA = [&](int rr, int kc, int kt) -> const u16* {
    if (MODE == 0) return A + (size_t)(bm + rr) * K + kt + kc;
    int m = bm + rr, kk = kt + kc;
    return A + ((((size_t)(m >> 12)) * 8 + (kk >> 6)) * 4096 + (m & 4095)) * 64 + (kk & 63);
  };
  u32x4 a00 = *(const u32x4*)srcA(r, c16, 0);
  u32x4 a01 = *(const u32x4*)(srcA(r, c16, 0) + 8);
  u32x4 a10 = *(const u32x4*)srcA(r + 64, c16, 0);
  u32x4 a11 = *(const u32x4*)(srcA(r + 64, c16, 0) + 8);
  const u16* pb0 = Bt + (size_t)(bn + r) * K + c16;
  const u16* pb1 = Bt + (size_t)(bn + r + 64) * K + c16;
  u32x4 b00 = *(const u32x4*)pb0;
  u32x4 b01 = *(const u32x4*)(pb0 + 8);
  u32x4 b10 = *(const u32x4*)pb1;
  u32x4 b11 = *(const u32x4*)(pb1 + 8);
  f32x4 acc[4][4] = {};
  for (int kt = 0; kt < K; kt += BK) {
    __syncthreads();
    *(u32x4*)&Al[r][c16] = a00;
    *(u32x4*)&Al[r][c16 + 8] = a01;
    *(u32x4*)&Al[r + 64][c16] = a10;
    *(u32x4*)&Al[r + 64][c16 + 8] = a11;
    *(u32x4*)&Bl[r][c16] = b00;
    *(u32x4*)&Bl[r][c16 + 8] = b01;
    *(u32x4*)&Bl[r + 64][c16] = b10;
    *(u32x4*)&Bl[r + 64][c16 + 8] = b11;
    __syncthreads();
    if (kt + BK < K) {
      int kn = kt + BK;
      a00 = *(const u32x4*)srcA(r, c16, kn);
      a01 = *(const u32x4*)(srcA(r, c16, kn) + 8);
      a10 = *(const u32x4*)srcA(r + 64, c16, kn);
      a11 = *(const u32x4*)(srcA(r + 64, c16, kn) + 8);
      b00 = *(const u32x4*)(pb0 + kn);
      b01 = *(const u32x4*)(pb0 + kn + 8);
      b10 = *(const u32x4*)(pb1 + kn);
      b11 = *(const u32x4*)(pb1 + kn + 8);
    }
#pragma unroll
    for (int ks = 0; ks < 2; ks++) {
      int ko = ks * 32 + 8 * g;
      bf16x8 af[4], bf_[4];
#pragma unroll
      for (int i = 0; i < 4; i++) af[i] = lds_frag(&Al[wm + i * 16 + l15][ko]);
#pragma unroll
      for (int i = 0; i < 4; i++) bf_[i] = lds_frag(&Bl[wn + i * 16 + l15][ko]);
#pragma unroll
      for (int mi = 0; mi < 4; mi++)
#pragma unroll
        for (int ni = 0; ni < 4; ni++) acc[mi][ni] = mfma16(af[mi], bf_[ni], acc[mi][ni]);
    }
  }
  if (MODE == 0) {
    int tensor = bn / 512;
    float scale = (tensor == 0) ? 0.125f : 1.0f;
    u16* base = (tensor == 0) ? oq : (tensor == 1 ? ok : ov);
#pragma unroll
    for (int mi = 0; mi < 4; mi++)
#pragma unroll
      for (int ni = 0; ni < 4; ni++) {
        int cw = (bn % 512) + wn + ni * 16 + l15;
        int h = cw >> 6, d = cw & 63;
#pragma unroll
        for (int rr = 0; rr < 4; rr++) {
          int m = bm + wm + mi * 16 + 4 * g + rr;
          int b = m >> 12, i = m & 4095;
          base[(((size_t)(b * 8 + h)) * 4096 + i) * 64 + d] = f2b(acc[mi][ni][rr] * scale);
        }
      }
  } else {
#pragma unroll
    for (int mi = 0; mi < 4; mi++)
#pragma unroll
      for (int ni = 0; ni < 4; ni++) {
        int col = bn + wn + ni * 16 + l15;
#pragma unroll
        for (int rr = 0; rr < 4; rr++) {
          int m = bm + wm + mi * 16 + 4 * g + rr;
          oc[(size_t)m * 512 + col] =
              acc[mi][ni][rr] + xres[(size_t)m * 512 + col] + bias[col];
        }
      }
  }
}

// ---------------- NS-chain GEMM, 64x64 tile, BK=64 (4 barriers/dispatch), padded LDS ----------------
// PREC=1: hi/lo inputs (3 MFMA/product). PREC=0: hi-only (1 MFMA/product).
// wlC/wlT: write the lo plane of C / T (skip when consumer is hi-only -> dead traffic).
template <int OMODE, int PREC>
__global__ __launch_bounds__(256) void ns_gemm(
    const u16* __restrict__ Ahg, const u16* __restrict__ Alg,
    const u16* __restrict__ Bhg, const u16* __restrict__ Blg, int K, int sA, int sB,
    u16* __restrict__ Ch, u16* __restrict__ Cl2, u16* __restrict__ Th, u16* __restrict__ Tl,
    float* __restrict__ Cf, u16* __restrict__ Tu,
    float cC, float aC, float cT, float aT, int wrC, int wrT, int wlC, int wlT) {
  __shared__ __align__(16) u16 Ahs[64][72], Als[64][72], Bhs[64][72], Bls[64][72];
  int bz = blockIdx.z;
  int tid = threadIdx.x, lane = tid & 63, wave = tid >> 6;
  int l15 = lane & 15, g = lane >> 4;
  int bm = blockIdx.x * 64, bn = blockIdx.y * 64;
  int wm = (wave >> 1) * 32, wn = (wave & 1) * 32;
  const u16* Ah0 = Ahg + (size_t)bz * sA;
  const u16* Al0 = Alg + (size_t)bz * sA;
  const u16* Bh0 = Bhg + (size_t)bz * sB;
  const u16* Bl0 = Blg + (size_t)bz * sB;
  int r = tid >> 2, c16 = (tid & 3) * 16;
  const u16* pa = Ah0 + (size_t)(bm + r) * K + c16;
  const u16* pal = Al0 + (size_t)(bm + r) * K + c16;
  const u16* pb = Bh0 + (size_t)(bn + r) * K + c16;
  const u16* pbl = Bl0 + (size_t)(bn + r) * K + c16;
  u32x4 ra0 = *(const u32x4*)pa, ra1 = *(const u32x4*)(pa + 8);
  u32x4 rc0 = *(const u32x4*)pb, rc1 = *(const u32x4*)(pb + 8);
  u32x4 rb0, rb1, rd0, rd1;
  if (PREC) {
    rb0 = *(const u32x4*)pal;
    rb1 = *(const u32x4*)(pal + 8);
    rd0 = *(const u32x4*)pbl;
    rd1 = *(const u32x4*)(pbl + 8);
  }
  f32x4 acc[2][2] = {};
  int nt = K >> 6;
  for (int t = 0; t < nt; t++) {
    __syncthreads();
    *(u32x4*)&Ahs[r][c16] = ra0;
    *(u32x4*)&Ahs[r][c16 + 8] = ra1;
    *(u32x4*)&Bhs[r][c16] = rc0;
    *(u32x4*)&Bhs[r][c16 + 8] = rc1;
    if (PREC) {
      *(u32x4*)&Als[r][c16] = rb0;
      *(u32x4*)&Als[r][c16 + 8] = rb1;
      *(u32x4*)&Bls[r][c16] = rd0;
      *(u32x4*)&Bls[r][c16 + 8] = rd1;
    }
    __syncthreads();
    if (t + 1 < nt) {
      int kt = (t + 1) << 6;
      ra0 = *(const u32x4*)(pa + kt);
      ra1 = *(const u32x4*)(pa + kt + 8);
      rc0 = *(const u32x4*)(pb + kt);
      rc1 = *(const u32x4*)(pb + kt + 8);
      if (PREC) {
        rb0 = *(const u32x4*)(pal + kt);
        rb1 = *(const u32x4*)(pal + kt + 8);
        rd0 = *(const u32x4*)(pbl + kt);
        rd1 = *(const u32x4*)(pbl + kt + 8);
      }
    }
#pragma unroll
    for (int ks = 0; ks < 2; ks++) {
      int ko = ks * 32 + 8 * g;
      bf16x8 ah[2], al[2], bh_[2], bl_[2];
#pragma unroll
      for (int i = 0; i < 2; i++) {
        int ro = wm + i * 16 + l15;
        int rn = wn + i * 16 + l15;
        ah[i] = lds_frag(&Ahs[ro][ko]);
        bh_[i] = lds_frag(&Bhs[rn][ko]);
        if (PREC) {
          al[i] = lds_frag(&Als[ro][ko]);
          bl_[i] = lds_frag(&Bls[rn][ko]);
        }
      }
#pragma unroll
      for (int mi = 0; mi < 2; mi++)
#pragma unroll
        for (int ni = 0; ni < 2; ni++) {
          acc[mi][ni] = mfma16(ah[mi], bh_[ni], acc[mi][ni]);
          if (PREC) {
            acc[mi][ni] = mfma16(ah[mi], bl_[ni], acc[mi][ni]);
            acc[mi][ni] = mfma16(al[mi], bh_[ni], acc[mi][ni]);
          }
        }
    }
  }
#pragma unroll
  for (int mi = 0; mi < 2; mi++)
#pragma unroll
    for (int ni = 0; ni < 2; ni++) {
      int r0 = bm + wm + mi * 16 + 4 * g;
      int cg = bn + wn + ni * 16 + l15;
      f32x4 a = acc[mi][ni];
      if (OMODE == 1) {
        float* c = Cf + (size_t)bz * 65536;
#pragma unroll
        for (int rr = 0; rr < 4; rr++)
          c[(size_t)(r0 + rr) * 256 + cg] = aC * a[rr] + ((r0 + rr) == cg ? cC : 0.f);
      } else if (OMODE == 2) {
        u16 pp[4];
#pragma unroll
        for (int rr = 0; rr < 4; rr++) pp[rr] = f2b(aT * a[rr]);
        u16* tp = Tu + ((((size_t)bz * 4 + (cg >> 4)) * 8 + (r0 >> 5)) * 512) +
                  (((r0 >> 3) & 3) * 128) + ((cg & 15) * 8) + (r0 & 7);
        *(u32*)tp = (u32)pp[0] | ((u32)pp[1] << 16);
        *(u32*)(tp + 2) = (u32)pp[2] | ((u32)pp[3] << 16);
      } else {
        if (wrC) {
#pragma unroll
          for (int rr = 0; rr < 4; rr++) {
            float v = aC * a[rr] + ((r0 + rr) == cg ? cC : 0.f);
            u16 hi = f2b(v);
            size_t idx = (size_t)bz * 65536 + (size_t)(r0 + rr) * 256 + cg;
            Ch[idx] = hi;
            if (wlC) Cl2[idx] = f2b(v - b2f(hi));
          }
        }
        if (wrT) {
          u16 ph[4], pl[4];
#pragma unroll
          for (int rr = 0; rr < 4; rr++) {
            float v = aT * a[rr] + ((r0 + rr) == cg ? cT : 0.f);
            ph[rr] = f2b(v);
            if (wlT) pl[rr] = f2b(v - b2f(ph[rr]));
          }
          size_t idx = (size_t)bz * 65536 + (size_t)cg * 256 + r0;
          *(u32*)&Th[idx] = (u32)ph[0] | ((u32)ph[1] << 16);
          *(u32*)&Th[idx + 2] = (u32)ph[2] | ((u32)ph[3] << 16);
          if (wlT) {
            *(u32*)&Tl[idx] = (u32)pl[0] | ((u32)pl[1] << 16);
            *(u32*)&Tl[idx + 2] = (u32)pl[2] | ((u32)pl[3] << 16);
          }
        }
      }
    }
}

// ---------------- row softmax over 256 (in place) + hi/lo plane output ----------------
__global__ __launch_bounds__(256) void softmax256(float* __restrict__ S,
                                                  u16* __restrict__ Sh,
                                                  u16* __restrict__ Sl) {
  int row = blockIdx.x * 4 + (threadIdx.x >> 6);
  int lane = threadIdx.x & 63;
  float* r = S + (size_t)row * 256;
  f32x4 vv = *(f32x4*)&r[lane * 4];
  float mx = wredmax(fmaxf(fmaxf(vv[0], vv[1]), fmaxf(vv[2], vv[3])));
  vv[0] = __expf(vv[0] - mx);
  vv[1] = __expf(vv[1] - mx);
  vv[2] = __expf(vv[2] - mx);
  vv[3] = __expf(vv[3] - mx);
  float sm = wredsum(vv[0] + vv[1] + vv[2] + vv[3]);
  vv *= (1.0f / sm);
  *(f32x4*)&r[lane * 4] = vv;
  u16 h[4], l[4];
#pragma unroll
  for (int e = 0; e < 4; e++) {
    h[e] = f2b(vv[e]);
    l[e] = f2b(vv[e] - b2f(h[e]));
  }
  size_t p = (size_t)row * 256 + lane * 4;
  *(u32*)&Sh[p] = (u32)h[0] | ((u32)h[1] << 16);
  *(u32*)&Sh[p + 2] = (u32)h[2] | ((u32)h[3] << 16);
  *(u32*)&Sl[p] = (u32)l[0] | ((u32)l[1] << 16);
  *(u32*)&Sl[p + 2] = (u32)l[2] | ((u32)l[3] << 16);
}

// ---------------- pinv scale, stage 1 ----------------
__global__ __launch_bounds__(256) void pinv_part(const float* __restrict__ mat,
                                                 float* __restrict__ colpart,
                                                 float* __restrict__ scal) {
  int blk = blockIdx.x;
  int bh = blk >> 3, ch = blk & 7;
  const float* m = mat + (size_t)bh * 65536 + (size_t)ch * 32 * 256;
  int tid = threadIdx.x, lane = tid & 63, wv = tid >> 6;
  float cp = 0.f;
#pragma unroll 4
  for (int r2 = 0; r2 < 32; r2++) cp += m[r2 * 256 + tid];
  colpart[(size_t)blk * 256 + tid] = cp;
  float rmax = 0.f;
#pragma unroll
  for (int rr = 0; rr < 8; rr++) {
    f32x4 v = *(const f32x4*)&m[(wv * 8 + rr) * 256 + lane * 4];
    float s = wredsum(v[0] + v[1] + v[2] + v[3]);
    rmax = fmaxf(rmax, s);
  }
  if (lane == 0) atomicMax((int*)&scal[1], __float_as_int(rmax));
}

// ---------------- pinv scale, stage 2 ----------------
__global__ __launch_bounds__(256) void pinv_fin(const float* __restrict__ colpart,
                                                float* __restrict__ scal) {
  int tid = threadIdx.x;
  float mx = 0.f;
  for (int bh = 0; bh < 32; bh++) {
    float s = 0.f;
#pragma unroll
    for (int ch = 0; ch < 8; ch++) s += colpart[((size_t)bh * 8 + ch) * 256 + tid];
    mx = fmaxf(mx, s);
  }
  mx = wredmax(mx);
  __shared__ float red[4];
  if ((tid & 63) == 0) red[tid >> 6] = mx;
  __syncthreads();
  if (tid == 0) {
    float a = fmaxf(fmaxf(red[0], red[1]), fmaxf(red[2], red[3]));
    atomicMax((int*)&scal[0], __float_as_int(a));
  }
}

// ---------------- pinv init: z = matT*s (zh), zT = mat*s (zth); lo planes are
// dead (overwritten by NS it=4 before first read) -> hi only ----------------
__global__ __launch_bounds__(256) void pinv_init(const float* __restrict__ mat,
                                                 const float* __restrict__ scal,
                                                 u16* __restrict__ zh,
                                                 u16* __restrict__ zth) {
  size_t idx = (size_t)blockIdx.x * 256 + threadIdx.x;
  int bh = (int)(idx >> 16);
  int i = (int)((idx >> 8) & 255), j = (int)(idx & 255);
  float s = 1.0f / (scal[0] * scal[1]);
  float val = mat[idx] * s;
  u16 hi = f2b(val);
  zth[idx] = hi;
  size_t tixd = ((size_t)bh << 16) + ((size_t)j << 8) + i;
  zh[tixd] = hi;
}

// ------- attn3 split-KV flash v3: merged ss chains (2x ILP, one LDS round-trip/tile) -------
__global__ __launch_bounds__(512) void attn3_split(const u16* __restrict__ qlh,
                                                   const u16* __restrict__ k,
                                                   const u16* __restrict__ vT,
                                                   float* __restrict__ pacc,
                                                   float* __restrict__ ml) {
  __shared__ __align__(16) u16 kb[64][72];
  __shared__ __align__(16) u16 vtb[64][72];
  __shared__ __align__(16) u16 Pb[8][32][72];
  int tid = threadIdx.x, lane = tid & 63, wv = tid >> 6;
  int l15 = lane & 15, g = lane >> 4;
  int bh = blockIdx.y, kvc = blockIdx.x;
  const u16* kb_g = k + ((size_t)bh * 4096 + (size_t)kvc * 512) * 64;
  const u16* vb_g = vT + (size_t)bh * 64 * 4096 + (size_t)kvc * 512;
  bf16x8 aq[2][2];
#pragma unroll
  for (int ss = 0; ss < 2; ss++) {
    const u16* qlp = qlh + ((size_t)bh * 256 + wv * 32 + ss * 16 + l15) * 64 + 8 * g;
    aq[ss][0] = g_frag(qlp);
    aq[ss][1] = g_frag(qlp + 32);
  }
  int sr = tid >> 3, sc = (tid & 7) * 8;
  u32x4 rk = *(const u32x4*)(kb_g + (size_t)sr * 64 + sc);
  u32x4 rv = *(const u32x4*)(vb_g + (size_t)sr * 4096 + sc);
  f32x4 minit = {-1e30f, -1e30f, -1e30f, -1e30f};
  f32x4 mreg[2] = {minit, minit};
  f32x4 lreg[2] = {};
  f32x4 oacc[2][4] = {};
  for (int t = 0; t < 8; t++) {
    __syncthreads();
    *(u32x4*)&kb[sr][sc] = rk;
    *(u32x4*)&vtb[sr][sc] = rv;
    __syncthreads();
    if (t < 7) {
      rk = *(const u32x4*)(kb_g + (size_t)(t + 1) * 4096 + (size_t)sr * 64 + sc);
      rv = *(const u32x4*)(vb_g + (size_t)(t + 1) * 64 + (size_t)sr * 4096 + sc);
    }
    // QK^T for both ss halves; kb fragments read once and shared
    f32x4 sa[2][4] = {};
#pragma unroll
    for (int nf = 0; nf < 4; nf++) {
      bf16x8 b0 = lds_frag(&kb[nf * 16 + l15][8 * g]);
      bf16x8 b1 = lds_frag(&kb[nf * 16 + l15][8 * g + 32]);
#pragma unroll
      for (int ss = 0; ss < 2; ss++) {
        sa[ss][nf] = mfma16(aq[ss][0], b0, sa[ss][nf]);
        sa[ss][nf] = mfma16(aq[ss][1], b1, sa[ss][nf]);
      }
    }
    // online softmax for both ss (independent chains -> 2x VALU ILP)
#pragma unroll
    for (int ss = 0; ss < 2; ss++) {
      f32x4 mn, corr;
#pragma unroll
      for (int r = 0; r < 4; r++) {
        float m_ = fmaxf(fmaxf(sa[ss][0][r], sa[ss][1][r]),
                         fmaxf(sa[ss][2][r], sa[ss][3][r]));
#pragma unroll
        for (int msk = 1; msk < 16; msk <<= 1) m_ = fmaxf(m_, __shfl_xor(m_, msk));
        mn[r] = fmaxf(mreg[ss][r], m_);
        corr[r] = __expf(mreg[ss][r] - mn[r]);
        mreg[ss][r] = mn[r];
      }
      f32x4 ps = {};
#pragma unroll
      for (int nf = 0; nf < 4; nf++)
#pragma unroll
        for (int r = 0; r < 4; r++) {
          sa[ss][nf][r] = __expf(sa[ss][nf][r] - mn[r]);
          ps[r] += sa[ss][nf][r];
        }
#pragma unroll
      for (int r = 0; r < 4; r++) {
#pragma unroll
        for (int msk = 1; msk < 16; msk <<= 1) ps[r] += __shfl_xor(ps[r], msk);
        lreg[ss][r] = lreg[ss][r] * corr[r] + ps[r];
      }
#pragma unroll
      for (int nf = 0; nf < 4; nf++) oacc[ss][nf] *= corr;
#pragma unroll
      for (int nf = 0; nf < 4; nf++)
#pragma unroll
        for (int r = 0; r < 4; r++)
          Pb[wv][ss * 16 + 4 * g + r][nf * 16 + l15] = f2b(sa[ss][nf][r]);
    }
    asm volatile("s_waitcnt lgkmcnt(0)" ::: "memory");
    __builtin_amdgcn_sched_barrier(0);
    bf16x8 ap[2][2];
#pragma unroll
    for (int ss = 0; ss < 2; ss++) {
      ap[ss][0] = lds_frag(&Pb[wv][ss * 16 + l15][8 * g]);
      ap[ss][1] = lds_frag(&Pb[wv][ss * 16 + l15][8 * g + 32]);
    }
    // PV for both ss; vtb fragments read once and shared
#pragma unroll
    for (int nf = 0; nf < 4; nf++) {
      bf16x8 b0 = lds_frag(&vtb[nf * 16 + l15][8 * g]);
      bf16x8 b1 = lds_frag(&vtb[nf * 16 + l15][8 * g + 32]);
#pragma unroll
      for (int ss = 0; ss < 2; ss++) {
        oacc[ss][nf] = mfma16(ap[ss][0], b0, oacc[ss][nf]);
        oacc[ss][nf] = mfma16(ap[ss][1], b1, oacc[ss][nf]);
      }
    }
  }
  size_t pb = (size_t)(bh * 8 + kvc) * 64;
#pragma unroll
  for (int ss = 0; ss < 2; ss++) {
    int qbase = wv * 32 + ss * 16;
#pragma unroll
    for (int nf = 0; nf < 4; nf++)
      *(f32x4*)&pacc[(pb + nf * 16 + l15) * 256 + qbase + 4 * g] = oacc[ss][nf];
    if (l15 == 0) {
#pragma unroll
      for (int r = 0; r < 4; r++) {
        size_t mi = ((size_t)(bh * 8 + kvc) * 256 + qbase + 4 * g + r) * 2;
        ml[mi] = mreg[ss][r];
        ml[mi + 1] = lreg[ss][r];
      }
    }
  }
}

// ------- attn3 combine: merge 8 kv-chunk partials -> w3 hi/lo planes -------
__global__ __launch_bounds__(256) void attn3_fin(const float* __restrict__ pacc,
                                                 const float* __restrict__ ml,
                                                 u16* __restrict__ w3h,
                                                 u16* __restrict__ w3l) {
  int dc = blockIdx.x, bh = blockIdx.y;
  int i = threadIdx.x;
  float m[8], l[8], w[8];
  float M = -1e30f;
#pragma unroll
  for (int kv = 0; kv < 8; kv++) {
    size_t mi = ((size_t)(bh * 8 + kv) * 256 + i) * 2;
    m[kv] = ml[mi];
    l[kv] = ml[mi + 1];
    M = fmaxf(M, m[kv]);
  }
  float den = 0.f;
#pragma unroll
  for (int kv = 0; kv < 8; kv++) {
    w[kv] = __expf(m[kv] - M);
    den += w[kv] * l[kv];
  }
  float inv = 1.0f / den;
#pragma unroll
  for (int dd = 0; dd < 16; dd++) {
    int d = dc * 16 + dd;
    float num = 0.f;
#pragma unroll
    for (int kv = 0; kv < 8; kv++)
      num += w[kv] * pacc[((size_t)(bh * 8 + kv) * 64 + d) * 256 + i];
    float val = num * inv;
    u16 hi = f2b(val);
    size_t o = ((size_t)bh * 64 + d) * 256 + i;
    w3h[o] = hi;
    w3l[o] = f2b(val - b2f(hi));
  }
}

// ------- attn1 (MFMA, barrier-free): conv phase hoisted before softmax -------
__global__ __launch_bounds__(256, 4) void attn1_mfma(const u16* __restrict__ q,
                                                     const u16* __restrict__ kF,
                                                     const u16* __restrict__ zwF,
                                                     const u16* __restrict__ vT,
                                                     const float* __restrict__ rker,
                                                     u16* __restrict__ out_h) {
  __shared__ __align__(16) u16 Pl[64][258];
  int tid = threadIdx.x, lane = tid & 63, wv = tid >> 6;
  int l15 = lane & 15, g = lane >> 4;
  int bh = blockIdx.y, h = bh & 7;
  int i0 = blockIdx.x * 64;
  const u16* qp = q + ((size_t)bh * 4096 + i0 + wv * 16 + l15) * 64 + 8 * g;
  bf16x8 aq0 = __builtin_bit_cast(bf16x8, *(const u32x4*)qp);
  bf16x8 aq1 = __builtin_bit_cast(bf16x8, *(const u32x4*)(qp + 32));
  u16 kb16 = (lane < 33) ? f2b(rker[h * 33 + lane]) : (u16)0;
  const u16* kfb = kF + (size_t)bh * 16384 + (size_t)lane * 8;
  f32x4 sacc[16] = {};
#pragma unroll
  for (int nf = 0; nf < 16; nf++) {
    bf16x8 b0 = g_frag(kfb + (nf * 2 + 0) * 512);
    bf16x8 b1 = g_frag(kfb + (nf * 2 + 1) * 512);
    sacc[nf] = mfma16(aq0, b0, sacc[nf]);
    sacc[nf] = mfma16(aq1, b1, sacc[nf]);
  }
  bf16x8 band[2];
#pragma unroll
  for (int ks = 0; ks < 2; ks++) {
    u16 bb[8];
#pragma unroll
    for (int j = 0; j < 8; j++) {
      int idx = 32 * ks + 8 * g + j - l15;
      u16 vsh = (u16)__shfl((int)kb16, idx & 63);
      bb[j] = (idx >= 0 && idx <= 32) ? vsh : (u16)0;
    }
    band[ks] = __builtin_bit_cast(bf16x8, *(u32x4*)bb);
  }
  f32x4 cacc[4] = {};
#pragma unroll
  for (int nf = 0; nf < 4; nf++) {
    int d = nf * 16 + l15;
    const u16* vp = vT + ((size_t)bh * 64 + d) * 4096;
#pragma unroll
    for (int ks = 0; ks < 2; ks++) {
      int col0 = i0 - 16 + 16 * wv + 32 * ks + 8 * g;
      bf16x8 vf;
      if (col0 >= 0 && col0 + 7 < 4096) {
        vf = g_frag(vp + col0);
      } else {
        u16 tmp[8];
#pragma unroll
        for (int j = 0; j < 8; j++) {
          int c = col0 + j;
          tmp[j] = (c >= 0 && c < 4096) ? vp[c] : (u16)0;
        }
        vf = __builtin_bit_cast(bf16x8, *(u32x4*)tmp);
      }
      cacc[nf] = mfma16(band[ks], vf, cacc[nf]);
    }
  }
  f32x4 mx;
#pragma unroll
  for (int r = 0; r < 4; r++) {
    float m_ = sacc[0][r];
#pragma unroll
    for (int nf = 1; nf < 16; nf++) m_ = fmaxf(m_, sacc[nf][r]);
#pragma unroll
    for (int msk = 1; msk < 16; msk <<= 1) m_ = fmaxf(m_, __shfl_xor(m_, msk));
    mx[r] = m_;
  }
  f32x4 ls = {};
#pragma unroll
  for (int nf = 0; nf < 16; nf++)
#pragma unroll
    for (int r = 0; r < 4; r++) {
      sacc[nf][r] = __expf(sacc[nf][r] - mx[r]);
      ls[r] += sacc[nf][r];
    }
  f32x4 invl;
#pragma unroll
  for (int r = 0; r < 4; r++) {
#pragma unroll
    for (int msk = 1; msk < 16; msk <<= 1) ls[r] += __shfl_xor(ls[r], msk);
    invl[r] = 1.0f / ls[r];
  }
#pragma unroll
  for (int nf = 0; nf < 16; nf++)
#pragma unroll
    for (int r = 0; r < 4; r++) Pl[wv * 16 + 4 * g + r][nf * 16 + l15] = f2b(sacc[nf][r]);
  asm volatile("s_waitcnt lgkmcnt(0)" ::: "memory");
  __builtin_amdgcn_sched_barrier(0);
  bf16x8 ap[8];
#pragma unroll
  for (int ks = 0; ks < 8; ks++) ap[ks] = lds_frag(&Pl[wv * 16 + l15][8 * g + 32 * ks]);
  const u16* zfb = zwF + (size_t)bh * 16384 + (size_t)lane * 8;
  f32x4 oacc[4] = {};
#pragma unroll
  for (int nf = 0; nf < 4; nf++) {
#pragma unroll
    for (int ks = 0; ks < 8; ks++) {
      bf16x8 b = g_frag(zfb + (nf * 8 + ks) * 512);
      oacc[nf] = mfma16(ap[ks], b, oacc[nf]);
    }
  }
#pragma unroll
  for (int nf = 0; nf < 4; nf++) {
    int colc = nf * 16 + l15;
#pragma unroll
    for (int r = 0; r < 4; r++) {
      float val = oacc[nf][r] * invl[r] + cacc[nf][r];
      out_h[((size_t)bh * 4096 + i0 + wv * 16 + 4 * g + r) * 64 + colc] = f2b(val);
    }
  }
}

extern "C" void kernel_launch(void* const* d_in, const int* in_sizes, int n_in,
                              void* d_out, int out_size, void* d_ws, size_t ws_size,
                              hipStream_t stream) {
  (void)in_sizes; (void)n_in; (void)out_size;
  const float* x = (const float*)d_in[0];
  const float* w_qkv = (const float*)d_in[1];
  const float* w_out = (const float*)d_in[2];
  const float* b_out = (const float*)d_in[3];
  const float* res_k = (const float*)d_in[4];
  const float* gamma = (const float*)d_in[5];
  const float* beta = (const float*)d_in[6];
  float* out = (float*)d_out;

  char* p = (char*)d_ws;
  auto alloc = [&](size_t bytes) {
    char* r = p;
    p += (bytes + 255) & ~(size_t)255;
    return r;
  };
  const size_t BH = 32;
  const size_t PLANE = BH * 65536 * 2;  // 4.19MB u16 plane [32][256][256]
  const size_t SMALL = BH * 256 * 64 * 2;
  u16* xn = (u16*)alloc(BH * 4096 * 64 * 2);  // aliased: vT after qkv
  u16* vT = xn;
  u16* wTq = (u16*)alloc(1536 * 512 * 2);
  u16* wTo = (u16*)alloc(512 * 512 * 2);
  u16* q = (u16*)alloc(BH * 4096 * 64 * 2);
  u16* k = (u16*)alloc(BH * 4096 * 64 * 2);
  u16* v = (u16*)alloc(BH * 4096 * 64 * 2);
  u16* qlh = (u16*)alloc(SMALL);
  u16* qll = (u16*)alloc(SMALL);
  u16* klh = (u16*)alloc(SMALL);
  u16* kll = (u16*)alloc(SMALL);
  u16* kF = (u16*)alloc(SMALL);
  float* mat = (float*)alloc(BH * 65536 * 4);  // aliased: t4 planes after pinv_init
  u16* t4h = (u16*)mat;
  u16* t4l = t4h + BH * 65536;
  u16* math_ = (u16*)alloc(PLANE);
  u16* matl = (u16*)alloc(PLANE);
  u16* zh = (u16*)alloc(PLANE);
  u16* zl = (u16*)alloc(PLANE);
  u16* zth = (u16*)alloc(PLANE);
  u16* ztl = (u16*)alloc(PLANE);
  char* slotB = alloc(4 * PLANE);  // mz hi/lo + s2 hi/lo; aliased: out_h
  u16* mzh = (u16*)slotB;
  u16* mzl = mzh + BH * 65536;
  u16* s2h = mzl + BH * 65536;
  u16* s2l = s2h + BH * 65536;
  u16* out_h = (u16*)slotB;
  u16* t3h = (u16*)alloc(PLANE);
  u16* t3l = (u16*)alloc(PLANE);
  u16* znh = (u16*)alloc(PLANE);
  u16* znl = (u16*)alloc(PLANE);
  u16* znth = (u16*)alloc(PLANE);
  u16* zntl = (u16*)alloc(PLANE);
  u16* w3h = (u16*)alloc(BH * 64 * 256 * 2);
  u16* w3l = (u16*)alloc(BH * 64 * 256 * 2);
  u16* zwF = (u16*)alloc(BH * 64 * 256 * 2);
  float* colpart = (float*)alloc(256 * 256 * 4);
  float* scal = (float*)alloc(256);
  if ((size_t)(p - (char*)d_ws) > ws_size) return;  // insufficient workspace
  // attn3 partials alias dead NS temporaries
  float* pacc = (float*)t3h;   // [32][8][64][256] f32
  float* mlbuf = (float*)znth; // [32][8][256][2] f32

  hipMemsetAsync(scal, 0, 8, stream);
  ln_k<<<16384, 256, 0, stream>>>(x, gamma, beta, xn);
  transpose_w<<<dim3(24, 8), 256, 0, stream>>>(w_qkv, wTq, 512, 1536);
  transpose_w<<<dim3(8, 8), 256, 0, stream>>>(w_out, wTo, 512, 512);
  gemm_bf16_nt<0><<<dim3(128, 12), 256, 0, stream>>>(xn, wTq, 512, q, k, v, nullptr,
                                                     nullptr, nullptr);
  landmark_mean<<<2048, 256, 0, stream>>>(q, qlh, qll, nullptr);
  landmark_mean<<<2048, 256, 0, stream>>>(k, klh, kll, kF);
  transpose_k<<<dim3(64, 32), 256, 0, stream>>>(v, vT);  // vT aliases xn (xn dead)
  // attn2 logits: mat = q_l @ k_l^T   (K=64, f32 out, hi/lo)
  ns_gemm<1, 1><<<dim3(4, 4, 32), 256, 0, stream>>>(
      qlh, qll, klh, kll, 64, 16384, 16384,
      nullptr, nullptr, nullptr, nullptr, mat, nullptr, 0.f, 1.f, 0.f, 0.f, 0, 0, 0, 0);
  softmax256<<<2048, 256, 0, stream>>>(mat, math_, matl);
  pinv_part<<<256, 256, 0, stream>>>(mat, colpart, scal);
  pinv_fin<<<1, 256, 0, stream>>>(colpart, scal);
  pinv_init<<<8192, 256, 0, stream>>>(mat, scal, zh, zth);
  u16 *zch = zh, *zcl = zl, *zcth = zth, *zctl = ztl;
  u16 *znh_ = znh, *znl_ = znl, *znth_ = znth, *zntl_ = zntl;
  for (int it = 0; it < 6; it++) {
    dim3 g44(4, 4, 32);
    if (it < 5) {
      // bf16 (hi-only) iterations: lo-plane writes are dead except it=4's d4
      // (whose zn/znt lo feed the hi/lo final iteration).
      int wl4 = (it == 4) ? 1 : 0;
      ns_gemm<0, 0><<<g44, 256, 0, stream>>>(
          math_, matl, zcth, zctl, 256, 65536, 65536,
          mzh, mzl, s2h, s2l, nullptr, nullptr, 0.f, 1.f, 7.f, -1.f, 1, 1, 0, 0);
      ns_gemm<0, 0><<<g44, 256, 0, stream>>>(
          mzh, mzl, s2h, s2l, 256, 65536, 65536,
          nullptr, nullptr, t3h, t3l, nullptr, nullptr, 0.f, 0.f, 15.f, -1.f, 0, 1, 0, 0);
      ns_gemm<0, 0><<<g44, 256, 0, stream>>>(
          mzh, mzl, t3h, t3l, 256, 65536, 65536,
          nullptr, nullptr, t4h, t4l, nullptr, nullptr, 0.f, 0.f, 13.f, -1.f, 0, 1, 0, 0);
      ns_gemm<0, 0><<<g44, 256, 0, stream>>>(
          zch, zcl, t4h, t4l, 256, 65536, 65536,
          znh_, znl_, znth_, zntl_, nullptr, nullptr, 0.f, 0.25f, 0.f, 0.25f, 1, 1,
          wl4, wl4);
    } else {
      // final iteration in hi/lo; d4's T output (znth_/zntl_) is never read -> wrT=0
      ns_gemm<0, 1><<<g44, 256, 0, stream>>>(
          math_, matl, zcth, zctl, 256, 65536, 65536,
          mzh, mzl, s2h, s2l, nullptr, nullptr, 0.f, 1.f, 7.f, -1.f, 1, 1, 1, 1);
      ns_gemm<0, 1><<<g44, 256, 0, stream>>>(
          mzh, mzl, s2h, s2l, 256, 65536, 65536,
          nullptr, nullptr, t3h, t3l, nullptr, nullptr, 0.f, 0.f, 15.f, -1.f, 0, 1, 1, 1);
      ns_gemm<0, 1><<<g44, 256, 0, stream>>>(
          mzh, mzl, t3h, t3l, 256, 65536, 65536,
          nullptr, nullptr, t4h, t4l, nullptr, nullptr, 0.f, 0.f, 13.f, -1.f, 0, 1, 1, 1);
      ns_gemm<0, 1><<<g44, 256, 0, stream>>>(
          zch, zcl, t4h, t4l, 256, 65536, 65536,
          znh_, znl_, znth_, zntl_, nullptr, nullptr, 0.f, 0.25f, 0.f, 0.25f, 1, 0, 1, 0);
    }
    u16* t;
    t = zch; zch = znh_; znh_ = t;
    t = zcl; zcl = znl_; znl_ = t;
    t = zcth; zcth = znth_; znth_ = t;
    t = zctl; zctl = zntl_; zntl_ = t;
  }
  attn3_split<<<dim3(8, 32), 512, 0, stream>>>(qlh, k, vT, pacc, mlbuf);
  attn3_fin<<<dim3(4, 32), 256, 0, stream>>>(pacc, mlbuf, w3h, w3l);
  // zwF = frag-ordered (z @ w3)^T  bf16 (hi/lo)
  ns_gemm<2, 1><<<dim3(4, 1, 32), 256, 0, stream>>>(
      zch, zcl, w3h, w3l, 256, 65536, 16384,
      nullptr, nullptr, nullptr, nullptr, nullptr, zwF, 0.f, 0.f, 0.f, 1.f, 0, 0, 0, 0);
  attn1_mfma<<<dim3(64, 32), 256, 0, stream>>>(q, kF, zwF, vT, res_k, out_h);
  gemm_bf16_nt<1><<<dim3(128, 4), 256, 0, stream>>>(out_h, wTo, 512, nullptr, nullptr,
                                                    nullptr, x, b_out, out);
}